// Round 4
// baseline (1966.420 us; speedup 1.0000x reference)
//
#include <hip/hip_runtime.h>
#include <hip/hip_bf16.h>

#define PAD 16   // pad each CSR segment to a multiple of 16 edges

// ---------------- graph preprocessing ----------------

__global__ void deg_kernel(const int* __restrict__ col, int* __restrict__ deg, int E) {
    int e = blockIdx.x * blockDim.x + threadIdx.x;
    if (e < E) atomicAdd(&deg[col[e]], 1);
}

__global__ void dinv_kernel(const int* __restrict__ deg, float* __restrict__ dinv,
                            float* __restrict__ dinv2, int N) {
    int n = blockIdx.x * blockDim.x + threadIdx.x;
    if (n < N) {
        int d = deg[n];
        float v = d > 0 ? rsqrtf((float)d) : 0.0f;
        dinv[n] = v;
        dinv2[n] = v * v;
    }
}

__device__ __forceinline__ int pad_up(int v) { return (v + (PAD - 1)) & ~(PAD - 1); }

// 3-phase exclusive scan over padded deg -> rowptr[N+1], chunk = 512
__global__ void scan_phaseA(const int* __restrict__ deg, int* __restrict__ chunkSum, int N) {
    int t = threadIdx.x;
    int idx = blockIdx.x * 512 + t;
    int v = idx < N ? pad_up(deg[idx]) : 0;
    for (int o = 32; o > 0; o >>= 1) v += __shfl_down(v, o, 64);
    __shared__ int wsum[8];
    if ((t & 63) == 0) wsum[t >> 6] = v;
    __syncthreads();
    if (t == 0) {
        int s = 0;
        for (int i = 0; i < 8; ++i) s += wsum[i];
        chunkSum[blockIdx.x] = s;
    }
}

__global__ void scan_phaseB(const int* __restrict__ chunkSum, int* __restrict__ chunkOff, int n) {
    __shared__ int a[256], b[256];
    int t = threadIdx.x;
    int v = t < n ? chunkSum[t] : 0;
    a[t] = v;
    __syncthreads();
    int* s = a; int* d = b;
    for (int off = 1; off < 256; off <<= 1) {
        int x = s[t];
        if (t >= off) x += s[t - off];
        d[t] = x;
        __syncthreads();
        int* tmp = s; s = d; d = tmp;
    }
    if (t < n) chunkOff[t] = s[t] - v;
}

__global__ void scan_phaseC(const int* __restrict__ deg, const int* __restrict__ chunkOff,
                            int* __restrict__ rowptr, int N) {
    __shared__ int a[512], b[512];
    int t = threadIdx.x;
    int idx = blockIdx.x * 512 + t;
    int v = idx < N ? pad_up(deg[idx]) : 0;
    a[t] = v;
    __syncthreads();
    int* s = a; int* d = b;
    for (int off = 1; off < 512; off <<= 1) {
        int x = s[t];
        if (t >= off) x += s[t - off];
        d[t] = x;
        __syncthreads();
        int* tmp = s; s = d; d = tmp;
    }
    if (idx < N) rowptr[idx] = chunkOff[blockIdx.x] + s[t] - v;
    if (idx == N - 1) rowptr[N] = chunkOff[blockIdx.x] + s[t];  // total padded edges
}

// scatter only the source index (4B/edge)
__global__ void fill_kernel(const int* __restrict__ row, const int* __restrict__ col,
                            const int* __restrict__ rowptr, int* __restrict__ cursor,
                            int* __restrict__ srcs, int E) {
    int e = blockIdx.x * blockDim.x + threadIdx.x;
    if (e < E) {
        int dn = col[e];
        int p = rowptr[dn] + atomicAdd(&cursor[dn], 1);
        srcs[p] = row[e];
    }
}

// pad slots point at row N of g (kept all-zero)
__global__ void pad_kernel(const int* __restrict__ deg, const int* __restrict__ rowptr,
                           int* __restrict__ srcs, int N) {
    int dn = blockIdx.x * blockDim.x + threadIdx.x;
    if (dn < N) {
        int p = rowptr[dn] + deg[dn];
        int p1 = rowptr[dn + 1];
        for (; p < p1; ++p) srcs[p] = N;
    }
}

// g0 = bf16(dinv ⊙ x), plus zeroed pad row N
__global__ void cvt_g_kernel(const float* __restrict__ x, const float* __restrict__ dinv,
                             __hip_bfloat16* __restrict__ g, int N) {
    int i = blockIdx.x * blockDim.x + threadIdx.x;
    int total = (N + 1) * 64;
    if (i < total) {
        float v = (i < N * 64) ? dinv[i >> 6] * x[i] : 0.0f;
        g[i] = __float2bfloat16(v);
    }
}

// h = tanh(acc + b); g = bf16(dinv ⊙ h)
__global__ void tanh_g_kernel(const float* __restrict__ acc, const float* __restrict__ b,
                              const float* __restrict__ dinv, float* __restrict__ h,
                              __hip_bfloat16* __restrict__ g, int total) {
    int i = blockIdx.x * blockDim.x + threadIdx.x;
    if (i < total) {
        float v = tanhf(acc[i] + b[i & 63]);
        h[i] = v;
        g[i] = __float2bfloat16(dinv[i >> 6] * v);
    }
}

// ---------------- dense helpers ----------------

// out = h @ W   (wave-per-node, W staged in LDS)
__global__ __launch_bounds__(256) void gemm_init_kernel(const float* __restrict__ h,
                                                        const float* __restrict__ W,
                                                        float* __restrict__ out, int n) {
    __shared__ float Wl[4096];
    for (int i = threadIdx.x; i < 4096; i += 256) Wl[i] = W[i];
    __syncthreads();
    int lane = threadIdx.x & 63;
    int gw = __builtin_amdgcn_readfirstlane((blockIdx.x * blockDim.x + threadIdx.x) >> 6);
    int nw = (gridDim.x * blockDim.x) >> 6;
    for (int d = gw; d < n; d += nw) {
        float v = h[(size_t)d * 64 + lane];
        float o = 0.f;
#pragma unroll
        for (int i = 0; i < 64; ++i) o += __shfl(v, i, 64) * Wl[i * 64 + lane];
        out[(size_t)d * 64 + lane] = o;
    }
}

// final: v = tanh(acc + b); out = v @ Wc + bc
__global__ __launch_bounds__(256) void tanh_gemm_bias_kernel(
        const float* __restrict__ acc, const float* __restrict__ b,
        const float* __restrict__ W, const float* __restrict__ bc,
        float* __restrict__ out, int n) {
    __shared__ float Wl[4096];
    for (int i = threadIdx.x; i < 4096; i += 256) Wl[i] = W[i];
    __syncthreads();
    int lane = threadIdx.x & 63;
    int gw = __builtin_amdgcn_readfirstlane((blockIdx.x * blockDim.x + threadIdx.x) >> 6);
    int nw = (gridDim.x * blockDim.x) >> 6;
    for (int d = gw; d < n; d += nw) {
        float v = tanhf(acc[(size_t)d * 64 + lane] + b[lane]);
        float o = bc[lane];
#pragma unroll
        for (int i = 0; i < 64; ++i) o += __shfl(v, i, 64) * Wl[i * 64 + lane];
        out[(size_t)d * 64 + lane] = o;
    }
}

// ---------------- propagation ----------------

__device__ __forceinline__ float bflo(unsigned u) { return __uint_as_float(u << 16); }
__device__ __forceinline__ float bfhi(unsigned u) { return __uint_as_float(u & 0xFFFF0000u); }

__device__ __forceinline__ unsigned short bfbits(float f) {
    __hip_bfloat16 h = __float2bfloat16(f);
    return *reinterpret_cast<unsigned short*>(&h);
}
__device__ __forceinline__ unsigned pack2(float a, float b) {
    return (unsigned)bfbits(a) | ((unsigned)bfbits(b) << 16);
}

#define UNPACK_ACC(Q)                                      \
    {                                                      \
        unsigned _x;                                       \
        _x = (Q).x; a0 += bflo(_x); a1 += bfhi(_x);        \
        _x = (Q).y; a2 += bflo(_x); a3 += bfhi(_x);        \
        _x = (Q).z; a4 += bflo(_x); a5 += bfhi(_x);        \
        _x = (Q).w; a6 += bflo(_x); a7 += bfhi(_x);        \
    }

// One hop: u = gather-sum of g rows; g_out = bf16(dinv2*u); out += (dinv*u) @ W.
// Gather layout: 8 lanes per edge, each lane loads uint4 = 8 bf16 feats.
// One wave instruction fetches 8 edges = 1 KB. Two per iter = 2 KB in flight.
__global__ __launch_bounds__(256) void hop_kernel(
        const __hip_bfloat16* __restrict__ g_in,
        const int* __restrict__ srcs, const int* __restrict__ rowptr,
        const float* __restrict__ dinv, const float* __restrict__ dinv2,
        const float* __restrict__ W,
        float* __restrict__ out, __hip_bfloat16* __restrict__ g_out, int n) {
    __shared__ float Wl[4096];
    for (int i = threadIdx.x; i < 4096; i += 256) Wl[i] = W[i];
    __syncthreads();
    const int lane = threadIdx.x & 63;
    const int sub  = lane >> 3;   // which edge in the 8-edge packet
    const int fq   = lane & 7;    // which 16B feature quad of the row
    const uint4* gq = (const uint4*)g_in;   // one row = 8 uint4
    int gw = __builtin_amdgcn_readfirstlane((blockIdx.x * blockDim.x + threadIdx.x) >> 6);
    int nw = (gridDim.x * blockDim.x) >> 6;
    for (int d = gw; d < n; d += nw) {
        int p0 = rowptr[d], p1 = rowptr[d + 1];
        float a0 = 0.f, a1 = 0.f, a2 = 0.f, a3 = 0.f,
              a4 = 0.f, a5 = 0.f, a6 = 0.f, a7 = 0.f;
        for (int p = p0; p < p1; p += 16) {
            int2 ss = *(const int2*)(srcs + p + 2 * sub);  // this subgroup's 2 edges
            uint4 qA = gq[(size_t)ss.x * 8 + fq];
            uint4 qB = gq[(size_t)ss.y * 8 + fq];
            UNPACK_ACC(qA);
            UNPACK_ACC(qB);
        }
        // reduce partial sums across the 8 subgroups (xor 8,16,32)
#pragma unroll
        for (int off = 8; off < 64; off <<= 1) {
            a0 += __shfl_xor(a0, off, 64);
            a1 += __shfl_xor(a1, off, 64);
            a2 += __shfl_xor(a2, off, 64);
            a3 += __shfl_xor(a3, off, 64);
            a4 += __shfl_xor(a4, off, 64);
            a5 += __shfl_xor(a5, off, 64);
            a6 += __shfl_xor(a6, off, 64);
            a7 += __shfl_xor(a7, off, 64);
        }
        float dv = dinv[d], dv2 = dinv2[d];
        // write g_out row d (lanes 0..7 cover the 8 feature quads)
        uint4 gp;
        gp.x = pack2(dv2 * a0, dv2 * a1);
        gp.y = pack2(dv2 * a2, dv2 * a3);
        gp.z = pack2(dv2 * a4, dv2 * a5);
        gp.w = pack2(dv2 * a6, dv2 * a7);
        if (sub == 0) ((uint4*)g_out)[(size_t)d * 8 + fq] = gp;
        // fused GEMM: h[i] = dv * a[i&7] held by lane i>>3
        float h0 = dv * a0, h1 = dv * a1, h2 = dv * a2, h3 = dv * a3;
        float h4 = dv * a4, h5 = dv * a5, h6 = dv * a6, h7 = dv * a7;
        float o = 0.f;
#pragma unroll
        for (int q = 0; q < 8; ++q) {
            o += __shfl(h0, q, 64) * Wl[(q * 8 + 0) * 64 + lane];
            o += __shfl(h1, q, 64) * Wl[(q * 8 + 1) * 64 + lane];
            o += __shfl(h2, q, 64) * Wl[(q * 8 + 2) * 64 + lane];
            o += __shfl(h3, q, 64) * Wl[(q * 8 + 3) * 64 + lane];
            o += __shfl(h4, q, 64) * Wl[(q * 8 + 4) * 64 + lane];
            o += __shfl(h5, q, 64) * Wl[(q * 8 + 5) * 64 + lane];
            o += __shfl(h6, q, 64) * Wl[(q * 8 + 6) * 64 + lane];
            o += __shfl(h7, q, 64) * Wl[(q * 8 + 7) * 64 + lane];
        }
        out[(size_t)d * 64 + lane] += o;
    }
}

// ---------------- launch ----------------

extern "C" void kernel_launch(void* const* d_in, const int* in_sizes, int n_in,
                              void* d_out, int out_size, void* d_ws, size_t ws_size,
                              hipStream_t stream) {
    const float* x  = (const float*)d_in[0];
    const int*   ei = (const int*)d_in[1];   // [2, E] int32
    const float* w1 = (const float*)d_in[2]; // [11,64,64]
    const float* b1 = (const float*)d_in[3];
    const float* w2 = (const float*)d_in[4]; // [4,64,64]
    const float* b2 = (const float*)d_in[5];
    const float* wc = (const float*)d_in[6];
    const float* bc = (const float*)d_in[7];
    float* out = (float*)d_out;

    const int N = in_sizes[0] / 64;
    const int E = in_sizes[1] / 2;
    const int K1 = 10, K2 = 3;
    const int* row = ei;
    const int* col = ei + E;
    const int Epad = E + (PAD - 1) * N + 64; // upper bound on padded edge count

    // workspace carve (256B aligned)
    char* base = (char*)d_ws;
    auto alloc = [&](size_t bytes) { void* p = (void*)base; base += (bytes + 255) & ~(size_t)255; return p; };
    int*   deg      = (int*)alloc((size_t)N * 4);
    int*   cursor   = (int*)alloc((size_t)N * 4);
    int*   rowptr   = (int*)alloc((size_t)(N + 1) * 4);
    int*   chunkSum = (int*)alloc(256 * 4);
    int*   chunkOff = (int*)alloc(256 * 4);
    float* dinv     = (float*)alloc((size_t)N * 4);
    float* dinv2    = (float*)alloc((size_t)N * 4);
    int*   srcs     = (int*)alloc((size_t)Epad * 4);
    __hip_bfloat16* gX = (__hip_bfloat16*)alloc((size_t)(N + 1) * 64 * 2);
    __hip_bfloat16* gA = (__hip_bfloat16*)alloc((size_t)(N + 1) * 64 * 2);
    __hip_bfloat16* gB = (__hip_bfloat16*)alloc((size_t)(N + 1) * 64 * 2);
    float* hA       = (float*)alloc((size_t)N * 64 * 4);

    const int numChunks = (N + 511) / 512;
    const int eBlocks = (E + 255) / 256;
    const int nBlocks = (N + 255) / 256;
    const int tBlocks = (N * 64 + 255) / 256;
    const int cBlocks = ((N + 1) * 64 + 255) / 256;
    const int gBlocks = 2048;

    // ---- graph preprocessing ----
    hipMemsetAsync(deg, 0, (size_t)N * 4, stream);
    hipMemsetAsync(cursor, 0, (size_t)N * 4, stream);
    hipMemsetAsync(gA + (size_t)N * 64, 0, 128, stream);  // pad row N stays zero
    hipMemsetAsync(gB + (size_t)N * 64, 0, 128, stream);
    deg_kernel<<<eBlocks, 256, 0, stream>>>(col, deg, E);
    dinv_kernel<<<nBlocks, 256, 0, stream>>>(deg, dinv, dinv2, N);
    scan_phaseA<<<numChunks, 512, 0, stream>>>(deg, chunkSum, N);
    scan_phaseB<<<1, 256, 0, stream>>>(chunkSum, chunkOff, numChunks);
    scan_phaseC<<<numChunks, 512, 0, stream>>>(deg, chunkOff, rowptr, N);
    fill_kernel<<<eBlocks, 256, 0, stream>>>(row, col, rowptr, cursor, srcs, E);
    pad_kernel<<<nBlocks, 256, 0, stream>>>(deg, rowptr, srcs, N);
    cvt_g_kernel<<<cBlocks, 256, 0, stream>>>(x, dinv, gX, N);

    // ---- layer 1: tanh(TAGConv(x; w1, b1)), K1 hops ----
    gemm_init_kernel<<<gBlocks, 256, 0, stream>>>(x, w1, out, N);
    {
        const __hip_bfloat16* gin = gX;
        for (int k = 1; k <= K1; ++k) {
            __hip_bfloat16* gout = (k & 1) ? gA : gB;
            hop_kernel<<<gBlocks, 256, 0, stream>>>(gin, srcs, rowptr, dinv, dinv2,
                                                    w1 + (size_t)k * 4096, out, gout, N);
            gin = gout;
        }
    }
    tanh_g_kernel<<<tBlocks, 256, 0, stream>>>(out, b1, dinv, hA, gX, N * 64);

    // ---- layer 2: tanh(TAGConv(hA; w2, b2)), K2 hops ----
    gemm_init_kernel<<<gBlocks, 256, 0, stream>>>(hA, w2, out, N);
    {
        const __hip_bfloat16* gin = gX;
        for (int k = 1; k <= K2; ++k) {
            __hip_bfloat16* gout = (k & 1) ? gA : gB;
            hop_kernel<<<gBlocks, 256, 0, stream>>>(gin, srcs, rowptr, dinv, dinv2,
                                                    w2 + (size_t)k * 4096, out, gout, N);
            gin = gout;
        }
    }

    // ---- tanh + head fused: d_out = tanh(out + b2) @ wc + bc ----
    tanh_gemm_bias_kernel<<<gBlocks, 256, 0, stream>>>(out, b2, wc, bc, out, N);
}

// Round 5
// 1591.211 us; speedup vs baseline: 1.2358x; 1.2358x over previous
//
#include <hip/hip_runtime.h>
#include <hip/hip_bf16.h>

#define PAD 16   // pad each CSR segment to a multiple of 16 edges

// ---------------- graph preprocessing ----------------

__global__ void deg_kernel(const int* __restrict__ col, int* __restrict__ deg, int E) {
    int e = blockIdx.x * blockDim.x + threadIdx.x;
    if (e < E) atomicAdd(&deg[col[e]], 1);
}

__global__ void dinv_kernel(const int* __restrict__ deg, float* __restrict__ dinv,
                            float* __restrict__ dinv2, int N) {
    int n = blockIdx.x * blockDim.x + threadIdx.x;
    if (n < N) {
        int d = deg[n];
        float v = d > 0 ? rsqrtf((float)d) : 0.0f;
        dinv[n] = v;
        dinv2[n] = v * v;
    }
}

__device__ __forceinline__ int pad_up(int v) { return (v + (PAD - 1)) & ~(PAD - 1); }

// 3-phase exclusive scan over padded deg -> rowptr[N+1], chunk = 512
__global__ void scan_phaseA(const int* __restrict__ deg, int* __restrict__ chunkSum, int N) {
    int t = threadIdx.x;
    int idx = blockIdx.x * 512 + t;
    int v = idx < N ? pad_up(deg[idx]) : 0;
    for (int o = 32; o > 0; o >>= 1) v += __shfl_down(v, o, 64);
    __shared__ int wsum[8];
    if ((t & 63) == 0) wsum[t >> 6] = v;
    __syncthreads();
    if (t == 0) {
        int s = 0;
        for (int i = 0; i < 8; ++i) s += wsum[i];
        chunkSum[blockIdx.x] = s;
    }
}

__global__ void scan_phaseB(const int* __restrict__ chunkSum, int* __restrict__ chunkOff, int n) {
    __shared__ int a[256], b[256];
    int t = threadIdx.x;
    int v = t < n ? chunkSum[t] : 0;
    a[t] = v;
    __syncthreads();
    int* s = a; int* d = b;
    for (int off = 1; off < 256; off <<= 1) {
        int x = s[t];
        if (t >= off) x += s[t - off];
        d[t] = x;
        __syncthreads();
        int* tmp = s; s = d; d = tmp;
    }
    if (t < n) chunkOff[t] = s[t] - v;
}

__global__ void scan_phaseC(const int* __restrict__ deg, const int* __restrict__ chunkOff,
                            int* __restrict__ rowptr, int N) {
    __shared__ int a[512], b[512];
    int t = threadIdx.x;
    int idx = blockIdx.x * 512 + t;
    int v = idx < N ? pad_up(deg[idx]) : 0;
    a[t] = v;
    __syncthreads();
    int* s = a; int* d = b;
    for (int off = 1; off < 512; off <<= 1) {
        int x = s[t];
        if (t >= off) x += s[t - off];
        d[t] = x;
        __syncthreads();
        int* tmp = s; s = d; d = tmp;
    }
    if (idx < N) rowptr[idx] = chunkOff[blockIdx.x] + s[t] - v;
    if (idx == N - 1) rowptr[N] = chunkOff[blockIdx.x] + s[t];  // total padded edges
}

// scatter only the source index (4B/edge)
__global__ void fill_kernel(const int* __restrict__ row, const int* __restrict__ col,
                            const int* __restrict__ rowptr, int* __restrict__ cursor,
                            int* __restrict__ srcs, int E) {
    int e = blockIdx.x * blockDim.x + threadIdx.x;
    if (e < E) {
        int dn = col[e];
        int p = rowptr[dn] + atomicAdd(&cursor[dn], 1);
        srcs[p] = row[e];
    }
}

// pad slots point at row N of g (kept all-zero)
__global__ void pad_kernel(const int* __restrict__ deg, const int* __restrict__ rowptr,
                           int* __restrict__ srcs, int N) {
    int dn = blockIdx.x * blockDim.x + threadIdx.x;
    if (dn < N) {
        int p = rowptr[dn] + deg[dn];
        int p1 = rowptr[dn + 1];
        for (; p < p1; ++p) srcs[p] = N;
    }
}

// ---------------- fused dense kernels ----------------

// layer-1 start: out = x @ W0 ; g = bf16(dinv ⊙ x)
__global__ __launch_bounds__(256) void gemm_g_kernel(const float* __restrict__ x,
                                                     const float* __restrict__ dinv,
                                                     const float* __restrict__ W0,
                                                     float* __restrict__ out,
                                                     __hip_bfloat16* __restrict__ g, int n) {
    __shared__ float Wl[4096];
    for (int i = threadIdx.x; i < 4096; i += 256) Wl[i] = W0[i];
    __syncthreads();
    int lane = threadIdx.x & 63;
    int gw = __builtin_amdgcn_readfirstlane((blockIdx.x * blockDim.x + threadIdx.x) >> 6);
    int nw = (gridDim.x * blockDim.x) >> 6;
    for (int d = gw; d < n; d += nw) {
        float v = x[(size_t)d * 64 + lane];
        g[(size_t)d * 64 + lane] = __float2bfloat16(dinv[d] * v);
        float o = 0.f;
#pragma unroll
        for (int i = 0; i < 64; ++i) o += __shfl(v, i, 64) * Wl[i * 64 + lane];
        out[(size_t)d * 64 + lane] = o;
    }
}

// layer boundary: h = tanh(acc + b) ; out = h @ W0next ; g = bf16(dinv ⊙ h)   (in-place out)
__global__ __launch_bounds__(256) void tanh_gemm_g_kernel(
        const float* __restrict__ acc, const float* __restrict__ b,
        const float* __restrict__ dinv, const float* __restrict__ W0,
        float* __restrict__ out, __hip_bfloat16* __restrict__ g, int n) {
    __shared__ float Wl[4096];
    for (int i = threadIdx.x; i < 4096; i += 256) Wl[i] = W0[i];
    __syncthreads();
    int lane = threadIdx.x & 63;
    int gw = __builtin_amdgcn_readfirstlane((blockIdx.x * blockDim.x + threadIdx.x) >> 6);
    int nw = (gridDim.x * blockDim.x) >> 6;
    for (int d = gw; d < n; d += nw) {
        float v = tanhf(acc[(size_t)d * 64 + lane] + b[lane]);
        g[(size_t)d * 64 + lane] = __float2bfloat16(dinv[d] * v);
        float o = 0.f;
#pragma unroll
        for (int i = 0; i < 64; ++i) o += __shfl(v, i, 64) * Wl[i * 64 + lane];
        out[(size_t)d * 64 + lane] = o;
    }
}

// final: v = tanh(acc + b); out = v @ Wc + bc
__global__ __launch_bounds__(256) void tanh_gemm_bias_kernel(
        const float* __restrict__ acc, const float* __restrict__ b,
        const float* __restrict__ W, const float* __restrict__ bc,
        float* __restrict__ out, int n) {
    __shared__ float Wl[4096];
    for (int i = threadIdx.x; i < 4096; i += 256) Wl[i] = W[i];
    __syncthreads();
    int lane = threadIdx.x & 63;
    int gw = __builtin_amdgcn_readfirstlane((blockIdx.x * blockDim.x + threadIdx.x) >> 6);
    int nw = (gridDim.x * blockDim.x) >> 6;
    for (int d = gw; d < n; d += nw) {
        float v = tanhf(acc[(size_t)d * 64 + lane] + b[lane]);
        float o = bc[lane];
#pragma unroll
        for (int i = 0; i < 64; ++i) o += __shfl(v, i, 64) * Wl[i * 64 + lane];
        out[(size_t)d * 64 + lane] = o;
    }
}

// ---------------- propagation ----------------

// One hop: u = gather-sum of g rows; g_out = bf16(dinv2*u); out += (dinv*u) @ W.
// Lane = feature. 16 independent 128B row-gathers in flight per wave iteration;
// srcs[p+j] is wave-uniform -> scalar loads (lgkmcnt, not vmcnt).
__global__ __launch_bounds__(256) void hop_kernel(
        const __hip_bfloat16* __restrict__ g_in,
        const int* __restrict__ srcs, const int* __restrict__ rowptr,
        const float* __restrict__ dinv, const float* __restrict__ dinv2,
        const float* __restrict__ W,
        float* __restrict__ out, __hip_bfloat16* __restrict__ g_out, int n) {
    __shared__ float Wl[4096];
    for (int i = threadIdx.x; i < 4096; i += 256) Wl[i] = W[i];
    __syncthreads();
    const int lane = threadIdx.x & 63;
    int gw = __builtin_amdgcn_readfirstlane((blockIdx.x * blockDim.x + threadIdx.x) >> 6);
    int nw = (gridDim.x * blockDim.x) >> 6;
    for (int d = gw; d < n; d += nw) {
        int p0 = rowptr[d], p1 = rowptr[d + 1];
        float agg = 0.f;
        for (int p = p0; p < p1; p += 16) {
            int s0  = srcs[p + 0],  s1  = srcs[p + 1],  s2  = srcs[p + 2],  s3  = srcs[p + 3];
            int s4  = srcs[p + 4],  s5  = srcs[p + 5],  s6  = srcs[p + 6],  s7  = srcs[p + 7];
            int s8  = srcs[p + 8],  s9  = srcs[p + 9],  s10 = srcs[p + 10], s11 = srcs[p + 11];
            int s12 = srcs[p + 12], s13 = srcs[p + 13], s14 = srcs[p + 14], s15 = srcs[p + 15];
            float v0  = __bfloat162float(g_in[(size_t)s0  * 64 + lane]);
            float v1  = __bfloat162float(g_in[(size_t)s1  * 64 + lane]);
            float v2  = __bfloat162float(g_in[(size_t)s2  * 64 + lane]);
            float v3  = __bfloat162float(g_in[(size_t)s3  * 64 + lane]);
            float v4  = __bfloat162float(g_in[(size_t)s4  * 64 + lane]);
            float v5  = __bfloat162float(g_in[(size_t)s5  * 64 + lane]);
            float v6  = __bfloat162float(g_in[(size_t)s6  * 64 + lane]);
            float v7  = __bfloat162float(g_in[(size_t)s7  * 64 + lane]);
            float v8  = __bfloat162float(g_in[(size_t)s8  * 64 + lane]);
            float v9  = __bfloat162float(g_in[(size_t)s9  * 64 + lane]);
            float v10 = __bfloat162float(g_in[(size_t)s10 * 64 + lane]);
            float v11 = __bfloat162float(g_in[(size_t)s11 * 64 + lane]);
            float v12 = __bfloat162float(g_in[(size_t)s12 * 64 + lane]);
            float v13 = __bfloat162float(g_in[(size_t)s13 * 64 + lane]);
            float v14 = __bfloat162float(g_in[(size_t)s14 * 64 + lane]);
            float v15 = __bfloat162float(g_in[(size_t)s15 * 64 + lane]);
            agg += v0;  agg += v1;  agg += v2;  agg += v3;
            agg += v4;  agg += v5;  agg += v6;  agg += v7;
            agg += v8;  agg += v9;  agg += v10; agg += v11;
            agg += v12; agg += v13; agg += v14; agg += v15;
        }
        g_out[(size_t)d * 64 + lane] = __float2bfloat16(dinv2[d] * agg);
        float h = dinv[d] * agg;
        float o = 0.f;
#pragma unroll
        for (int i = 0; i < 64; ++i) o += __shfl(h, i, 64) * Wl[i * 64 + lane];
        out[(size_t)d * 64 + lane] += o;
    }
}

// ---------------- launch ----------------

extern "C" void kernel_launch(void* const* d_in, const int* in_sizes, int n_in,
                              void* d_out, int out_size, void* d_ws, size_t ws_size,
                              hipStream_t stream) {
    const float* x  = (const float*)d_in[0];
    const int*   ei = (const int*)d_in[1];   // [2, E] int32
    const float* w1 = (const float*)d_in[2]; // [11,64,64]
    const float* b1 = (const float*)d_in[3];
    const float* w2 = (const float*)d_in[4]; // [4,64,64]
    const float* b2 = (const float*)d_in[5];
    const float* wc = (const float*)d_in[6];
    const float* bc = (const float*)d_in[7];
    float* out = (float*)d_out;

    const int N = in_sizes[0] / 64;
    const int E = in_sizes[1] / 2;
    const int K1 = 10, K2 = 3;
    const int* row = ei;
    const int* col = ei + E;
    const int Epad = E + (PAD - 1) * N + 64; // upper bound on padded edge count

    // workspace carve (256B aligned)
    char* base = (char*)d_ws;
    auto alloc = [&](size_t bytes) { void* p = (void*)base; base += (bytes + 255) & ~(size_t)255; return p; };
    int*   deg      = (int*)alloc((size_t)N * 4);
    int*   cursor   = (int*)alloc((size_t)N * 4);
    int*   rowptr   = (int*)alloc((size_t)(N + 1) * 4);
    int*   chunkSum = (int*)alloc(256 * 4);
    int*   chunkOff = (int*)alloc(256 * 4);
    float* dinv     = (float*)alloc((size_t)N * 4);
    float* dinv2    = (float*)alloc((size_t)N * 4);
    int*   srcs     = (int*)alloc((size_t)Epad * 4);
    __hip_bfloat16* gX = (__hip_bfloat16*)alloc((size_t)(N + 1) * 64 * 2);
    __hip_bfloat16* gA = (__hip_bfloat16*)alloc((size_t)(N + 1) * 64 * 2);
    __hip_bfloat16* gB = (__hip_bfloat16*)alloc((size_t)(N + 1) * 64 * 2);

    const int numChunks = (N + 511) / 512;
    const int eBlocks = (E + 255) / 256;
    const int nBlocks = (N + 255) / 256;
    const int gBlocks = 2048;

    // ---- graph preprocessing ----
    hipMemsetAsync(deg, 0, (size_t)N * 4, stream);
    hipMemsetAsync(cursor, 0, (size_t)N * 4, stream);
    hipMemsetAsync(gX + (size_t)N * 64, 0, 128, stream);  // pad row N stays zero
    hipMemsetAsync(gA + (size_t)N * 64, 0, 128, stream);
    hipMemsetAsync(gB + (size_t)N * 64, 0, 128, stream);
    deg_kernel<<<eBlocks, 256, 0, stream>>>(col, deg, E);
    dinv_kernel<<<nBlocks, 256, 0, stream>>>(deg, dinv, dinv2, N);
    scan_phaseA<<<numChunks, 512, 0, stream>>>(deg, chunkSum, N);
    scan_phaseB<<<1, 256, 0, stream>>>(chunkSum, chunkOff, numChunks);
    scan_phaseC<<<numChunks, 512, 0, stream>>>(deg, chunkOff, rowptr, N);
    fill_kernel<<<eBlocks, 256, 0, stream>>>(row, col, rowptr, cursor, srcs, E);
    pad_kernel<<<nBlocks, 256, 0, stream>>>(deg, rowptr, srcs, N);

    // ---- layer 1: tanh(TAGConv(x; w1, b1)), K1 hops ----
    gemm_g_kernel<<<gBlocks, 256, 0, stream>>>(x, dinv, w1, out, gX, N);
    {
        const __hip_bfloat16* gin = gX;
        for (int k = 1; k <= K1; ++k) {
            __hip_bfloat16* gout = (k & 1) ? gA : gB;
            hop_kernel<<<gBlocks, 256, 0, stream>>>(gin, srcs, rowptr, dinv, dinv2,
                                                    w1 + (size_t)k * 4096, out, gout, N);
            gin = gout;
        }
    }

    // ---- layer boundary: h=tanh(out+b1); out = h@w2[0]; gX = bf16(dinv*h) ----
    tanh_gemm_g_kernel<<<gBlocks, 256, 0, stream>>>(out, b1, dinv, w2, out, gX, N);

    // ---- layer 2 hops ----
    {
        const __hip_bfloat16* gin = gX;
        for (int k = 1; k <= K2; ++k) {
            __hip_bfloat16* gout = (k & 1) ? gA : gB;
            hop_kernel<<<gBlocks, 256, 0, stream>>>(gin, srcs, rowptr, dinv, dinv2,
                                                    w2 + (size_t)k * 4096, out, gout, N);
            gin = gout;
        }
    }

    // ---- tanh + head fused: d_out = tanh(out + b2) @ wc + bc ----
    tanh_gemm_bias_kernel<<<gBlocks, 256, 0, stream>>>(out, b2, wc, bc, out, N);
}

// Round 6
// 826.972 us; speedup vs baseline: 2.3779x; 1.9241x over previous
//
#include <hip/hip_runtime.h>
#include <hip/hip_bf16.h>

#define PAD 16   // pad each CSR segment to a multiple of 16 edges

typedef __attribute__((ext_vector_type(8))) short short8;
typedef __attribute__((ext_vector_type(4))) float float4v;

__device__ __forceinline__ short8 as_s8(uint4 v) {
    union { uint4 u; short8 s; } x; x.u = v; return x.s;
}

// ---------------- graph preprocessing ----------------

__global__ void deg_kernel(const int* __restrict__ col, int* __restrict__ deg, int E) {
    int e = blockIdx.x * blockDim.x + threadIdx.x;
    if (e < E) atomicAdd(&deg[col[e]], 1);
}

__global__ void dinv_kernel(const int* __restrict__ deg, float* __restrict__ dinv,
                            float* __restrict__ dinv2, float* __restrict__ sdeg, int N) {
    int n = blockIdx.x * blockDim.x + threadIdx.x;
    if (n < N) {
        int d = deg[n];
        float v = d > 0 ? rsqrtf((float)d) : 0.0f;
        dinv[n] = v;
        dinv2[n] = v * v;
        sdeg[n] = d > 0 ? sqrtf((float)d) : 0.0f;
    }
}

__device__ __forceinline__ int pad_up(int v) { return (v + (PAD - 1)) & ~(PAD - 1); }

// 3-phase exclusive scan over padded deg -> rowptr[N+1], chunk = 512
__global__ void scan_phaseA(const int* __restrict__ deg, int* __restrict__ chunkSum, int N) {
    int t = threadIdx.x;
    int idx = blockIdx.x * 512 + t;
    int v = idx < N ? pad_up(deg[idx]) : 0;
    for (int o = 32; o > 0; o >>= 1) v += __shfl_down(v, o, 64);
    __shared__ int wsum[8];
    if ((t & 63) == 0) wsum[t >> 6] = v;
    __syncthreads();
    if (t == 0) {
        int s = 0;
        for (int i = 0; i < 8; ++i) s += wsum[i];
        chunkSum[blockIdx.x] = s;
    }
}

__global__ void scan_phaseB(const int* __restrict__ chunkSum, int* __restrict__ chunkOff, int n) {
    __shared__ int a[256], b[256];
    int t = threadIdx.x;
    int v = t < n ? chunkSum[t] : 0;
    a[t] = v;
    __syncthreads();
    int* s = a; int* d = b;
    for (int off = 1; off < 256; off <<= 1) {
        int x = s[t];
        if (t >= off) x += s[t - off];
        d[t] = x;
        __syncthreads();
        int* tmp = s; s = d; d = tmp;
    }
    if (t < n) chunkOff[t] = s[t] - v;
}

__global__ void scan_phaseC(const int* __restrict__ deg, const int* __restrict__ chunkOff,
                            int* __restrict__ rowptr, int N) {
    __shared__ int a[512], b[512];
    int t = threadIdx.x;
    int idx = blockIdx.x * 512 + t;
    int v = idx < N ? pad_up(deg[idx]) : 0;
    a[t] = v;
    __syncthreads();
    int* s = a; int* d = b;
    for (int off = 1; off < 512; off <<= 1) {
        int x = s[t];
        if (t >= off) x += s[t - off];
        d[t] = x;
        __syncthreads();
        int* tmp = s; s = d; d = tmp;
    }
    if (idx < N) rowptr[idx] = chunkOff[blockIdx.x] + s[t] - v;
    if (idx == N - 1) rowptr[N] = chunkOff[blockIdx.x] + s[t];
}

__global__ void fill_kernel(const int* __restrict__ row, const int* __restrict__ col,
                            const int* __restrict__ rowptr, int* __restrict__ cursor,
                            int* __restrict__ srcs, int E) {
    int e = blockIdx.x * blockDim.x + threadIdx.x;
    if (e < E) {
        int dn = col[e];
        int p = rowptr[dn] + atomicAdd(&cursor[dn], 1);
        srcs[p] = row[e];
    }
}

__global__ void pad_kernel(const int* __restrict__ deg, const int* __restrict__ rowptr,
                           int* __restrict__ srcs, int N) {
    int dn = blockIdx.x * blockDim.x + threadIdx.x;
    if (dn < N) {
        int p = rowptr[dn] + deg[dn];
        int p1 = rowptr[dn + 1];
        for (; p < p1; ++p) srcs[p] = N;
    }
}

// Convert w1 (11 GEMMs) + w2 (4 GEMMs) into MFMA B-fragment order, bf16.
// wf[g][((t*4+u)*64 + lane)*8 + j] = bf16(W_g[k][n]), k=t*32+(lane>>4)*8+j, n=u*16+(lane&15)
__global__ void wcvt_kernel(const float* __restrict__ w1, const float* __restrict__ w2,
                            __hip_bfloat16* __restrict__ wf) {
    int idx = blockIdx.x * blockDim.x + threadIdx.x;
    if (idx >= 15 * 4096) return;
    int g = idx >> 12, r = idx & 4095;
    int j = r & 7, lane = (r >> 3) & 63, u = (r >> 9) & 3, t = r >> 11;
    int k = t * 32 + (lane >> 4) * 8 + j;
    int n = u * 16 + (lane & 15);
    const float* W = (g < 11) ? (w1 + (size_t)g * 4096) : (w2 + (size_t)(g - 11) * 4096);
    wf[idx] = __float2bfloat16(W[k * 64 + n]);
}

// zero pad row N of all nbuf g buffers
__global__ void zero_pads_kernel(__hip_bfloat16* __restrict__ gbase, size_t gstride,
                                 int nbuf, int N) {
    int i = blockIdx.x * blockDim.x + threadIdx.x;
    int b = i >> 6;
    if (b < nbuf) gbase[(size_t)b * gstride + (size_t)N * 64 + (i & 63)] = __float2bfloat16(0.0f);
}

// g0 = bf16(dinv ⊙ x)
__global__ void cvt_g_kernel(const float* __restrict__ x, const float* __restrict__ dinv,
                             __hip_bfloat16* __restrict__ g, int N) {
    int i = blockIdx.x * blockDim.x + threadIdx.x;
    if (i < N * 64) g[i] = __float2bfloat16(dinv[i >> 6] * x[i]);
}

// ---------------- propagation: pure gather hop ----------------
// u = sum of g_in rows over incoming edges; g_out = bf16(dinv2 * u)

__global__ __launch_bounds__(256) void hop_kernel(
        const __hip_bfloat16* __restrict__ g_in,
        const int* __restrict__ srcs, const int* __restrict__ rowptr,
        const float* __restrict__ dinv2,
        __hip_bfloat16* __restrict__ g_out, int n) {
    const int lane = threadIdx.x & 63;
    int gw = __builtin_amdgcn_readfirstlane((blockIdx.x * blockDim.x + threadIdx.x) >> 6);
    int nw = (gridDim.x * blockDim.x) >> 6;
    for (int d = gw; d < n; d += nw) {
        int p0 = rowptr[d], p1 = rowptr[d + 1];
        float agg = 0.f;
        for (int p = p0; p < p1; p += 16) {
            int s0  = srcs[p + 0],  s1  = srcs[p + 1],  s2  = srcs[p + 2],  s3  = srcs[p + 3];
            int s4  = srcs[p + 4],  s5  = srcs[p + 5],  s6  = srcs[p + 6],  s7  = srcs[p + 7];
            int s8  = srcs[p + 8],  s9  = srcs[p + 9],  s10 = srcs[p + 10], s11 = srcs[p + 11];
            int s12 = srcs[p + 12], s13 = srcs[p + 13], s14 = srcs[p + 14], s15 = srcs[p + 15];
            float v0  = __bfloat162float(g_in[(size_t)s0  * 64 + lane]);
            float v1  = __bfloat162float(g_in[(size_t)s1  * 64 + lane]);
            float v2  = __bfloat162float(g_in[(size_t)s2  * 64 + lane]);
            float v3  = __bfloat162float(g_in[(size_t)s3  * 64 + lane]);
            float v4  = __bfloat162float(g_in[(size_t)s4  * 64 + lane]);
            float v5  = __bfloat162float(g_in[(size_t)s5  * 64 + lane]);
            float v6  = __bfloat162float(g_in[(size_t)s6  * 64 + lane]);
            float v7  = __bfloat162float(g_in[(size_t)s7  * 64 + lane]);
            float v8  = __bfloat162float(g_in[(size_t)s8  * 64 + lane]);
            float v9  = __bfloat162float(g_in[(size_t)s9  * 64 + lane]);
            float v10 = __bfloat162float(g_in[(size_t)s10 * 64 + lane]);
            float v11 = __bfloat162float(g_in[(size_t)s11 * 64 + lane]);
            float v12 = __bfloat162float(g_in[(size_t)s12 * 64 + lane]);
            float v13 = __bfloat162float(g_in[(size_t)s13 * 64 + lane]);
            float v14 = __bfloat162float(g_in[(size_t)s14 * 64 + lane]);
            float v15 = __bfloat162float(g_in[(size_t)s15 * 64 + lane]);
            agg += v0;  agg += v1;  agg += v2;  agg += v3;
            agg += v4;  agg += v5;  agg += v6;  agg += v7;
            agg += v8;  agg += v9;  agg += v10; agg += v11;
            agg += v12; agg += v13; agg += v14; agg += v15;
        }
        g_out[(size_t)d * 64 + lane] = __float2bfloat16(dinv2[d] * agg);
    }
}

// ---------------- deferred multi-GEMM (MFMA) ----------------
// acc = sum_g G_g @ W_g   (16-node tile per wave, 4 n-tiles of 16)
// val = sdeg[node]*acc + bias[n];  tv = tanh(val)
// mode 0: gout[node][n] = bf16(dinv[node]*tv)     (layer boundary)
// mode 1: vout[node][n] = tv                       (pre-head)

__global__ __launch_bounds__(256) void final_kernel(
        const __hip_bfloat16* gbase, size_t gstride, int ngemm,
        const __hip_bfloat16* __restrict__ wf,
        const float* __restrict__ sdeg, const float* __restrict__ bias,
        const float* __restrict__ dinv,
        __hip_bfloat16* gout, float* vout, int mode, int ntiles) {
    const int lane = threadIdx.x & 63;
    const int col = lane & 15, quad = lane >> 4;
    int wv = (blockIdx.x * blockDim.x + threadIdx.x) >> 6;
    int nwv = (gridDim.x * blockDim.x) >> 6;
    const uint4* wfq = (const uint4*)wf;
    for (int tile = wv; tile < ntiles; tile += nwv) {
        int base = tile * 16;
        float4v acc0 = {0.f, 0.f, 0.f, 0.f};
        float4v acc1 = {0.f, 0.f, 0.f, 0.f};
        float4v acc2 = {0.f, 0.f, 0.f, 0.f};
        float4v acc3 = {0.f, 0.f, 0.f, 0.f};
        for (int g = 0; g < ngemm; ++g) {
            const uint4* ga = (const uint4*)(gbase + (size_t)g * gstride);
            const uint4* wg = wfq + (size_t)g * 512;
#pragma unroll
            for (int t = 0; t < 2; ++t) {
                short8 a = as_s8(ga[(size_t)(base + col) * 8 + t * 4 + quad]);
                short8 b0 = as_s8(wg[(t * 4 + 0) * 64 + lane]);
                short8 b1 = as_s8(wg[(t * 4 + 1) * 64 + lane]);
                short8 b2 = as_s8(wg[(t * 4 + 2) * 64 + lane]);
                short8 b3 = as_s8(wg[(t * 4 + 3) * 64 + lane]);
                acc0 = __builtin_amdgcn_mfma_f32_16x16x32_bf16(a, b0, acc0, 0, 0, 0);
                acc1 = __builtin_amdgcn_mfma_f32_16x16x32_bf16(a, b1, acc1, 0, 0, 0);
                acc2 = __builtin_amdgcn_mfma_f32_16x16x32_bf16(a, b2, acc2, 0, 0, 0);
                acc3 = __builtin_amdgcn_mfma_f32_16x16x32_bf16(a, b3, acc3, 0, 0, 0);
            }
        }
        // epilogue
#pragma unroll
        for (int r = 0; r < 4; ++r) {
            int nd = base + quad * 4 + r;
            float sd = sdeg[nd];
            float f0 = tanhf(sd * acc0[r] + bias[0 * 16 + col]);
            float f1 = tanhf(sd * acc1[r] + bias[1 * 16 + col]);
            float f2 = tanhf(sd * acc2[r] + bias[2 * 16 + col]);
            float f3 = tanhf(sd * acc3[r] + bias[3 * 16 + col]);
            if (mode == 0) {
                float dv = dinv[nd];
                gout[(size_t)nd * 64 + 0 * 16 + col] = __float2bfloat16(dv * f0);
                gout[(size_t)nd * 64 + 1 * 16 + col] = __float2bfloat16(dv * f1);
                gout[(size_t)nd * 64 + 2 * 16 + col] = __float2bfloat16(dv * f2);
                gout[(size_t)nd * 64 + 3 * 16 + col] = __float2bfloat16(dv * f3);
            } else {
                vout[(size_t)nd * 64 + 0 * 16 + col] = f0;
                vout[(size_t)nd * 64 + 1 * 16 + col] = f1;
                vout[(size_t)nd * 64 + 2 * 16 + col] = f2;
                vout[(size_t)nd * 64 + 3 * 16 + col] = f3;
            }
        }
    }
}

// ---------------- head: out = v @ Wc + bc ----------------

__global__ __launch_bounds__(256) void gemm_bias_kernel(const float* __restrict__ h,
                                                        const float* __restrict__ W,
                                                        const float* __restrict__ b,
                                                        float* __restrict__ out, int n) {
    __shared__ float Wl[4096];
    for (int i = threadIdx.x; i < 4096; i += 256) Wl[i] = W[i];
    __syncthreads();
    int lane = threadIdx.x & 63;
    int gw = __builtin_amdgcn_readfirstlane((blockIdx.x * blockDim.x + threadIdx.x) >> 6);
    int nw = (gridDim.x * blockDim.x) >> 6;
    for (int d = gw; d < n; d += nw) {
        float v = h[(size_t)d * 64 + lane];
        float o = b[lane];
#pragma unroll
        for (int i = 0; i < 64; ++i) o += __shfl(v, i, 64) * Wl[i * 64 + lane];
        out[(size_t)d * 64 + lane] = o;
    }
}

// ---------------- launch ----------------

extern "C" void kernel_launch(void* const* d_in, const int* in_sizes, int n_in,
                              void* d_out, int out_size, void* d_ws, size_t ws_size,
                              hipStream_t stream) {
    const float* x  = (const float*)d_in[0];
    const int*   ei = (const int*)d_in[1];   // [2, E] int32
    const float* w1 = (const float*)d_in[2]; // [11,64,64]
    const float* b1 = (const float*)d_in[3];
    const float* w2 = (const float*)d_in[4]; // [4,64,64]
    const float* b2 = (const float*)d_in[5];
    const float* wc = (const float*)d_in[6];
    const float* bc = (const float*)d_in[7];
    float* out = (float*)d_out;

    const int N = in_sizes[0] / 64;
    const int E = in_sizes[1] / 2;
    const int K1 = 10, K2 = 3;
    const int* row = ei;
    const int* col = ei + E;
    const int Epad = E + (PAD - 1) * N + 64;
    const int NBUF = 11;
    const size_t gstride = (((size_t)(N + 1) * 64) + 127) & ~(size_t)127;  // elems, 256B-aligned

    // workspace carve (256B aligned)
    char* base = (char*)d_ws;
    auto alloc = [&](size_t bytes) { void* p = (void*)base; base += (bytes + 255) & ~(size_t)255; return p; };
    int*   deg      = (int*)alloc((size_t)N * 4);
    int*   cursor   = (int*)alloc((size_t)N * 4);
    int*   rowptr   = (int*)alloc((size_t)(N + 1) * 4);
    int*   chunkSum = (int*)alloc(256 * 4);
    int*   chunkOff = (int*)alloc(256 * 4);
    float* dinv     = (float*)alloc((size_t)N * 4);
    float* dinv2    = (float*)alloc((size_t)N * 4);
    float* sdeg     = (float*)alloc((size_t)N * 4);
    int*   srcs     = (int*)alloc((size_t)Epad * 4);
    __hip_bfloat16* wf    = (__hip_bfloat16*)alloc((size_t)15 * 4096 * 2);
    __hip_bfloat16* gbase = (__hip_bfloat16*)alloc((size_t)NBUF * gstride * 2);

    auto G = [&](int k) { return gbase + (size_t)k * gstride; };
    float* vbuf = (float*)G(5);  // reuse G(5..6): 2*gstride*2B >= N*64*4B

    const int numChunks = (N + 511) / 512;
    const int eBlocks = (E + 255) / 256;
    const int nBlocks = (N + 255) / 256;
    const int xBlocks = (N * 64 + 255) / 256;
    const int gBlocks = 2048;
    const int ntiles = (N + 15) / 16;

    // ---- graph preprocessing ----
    hipMemsetAsync(deg, 0, (size_t)N * 4, stream);
    hipMemsetAsync(cursor, 0, (size_t)N * 4, stream);
    deg_kernel<<<eBlocks, 256, 0, stream>>>(col, deg, E);
    dinv_kernel<<<nBlocks, 256, 0, stream>>>(deg, dinv, dinv2, sdeg, N);
    scan_phaseA<<<numChunks, 512, 0, stream>>>(deg, chunkSum, N);
    scan_phaseB<<<1, 256, 0, stream>>>(chunkSum, chunkOff, numChunks);
    scan_phaseC<<<numChunks, 512, 0, stream>>>(deg, chunkOff, rowptr, N);
    fill_kernel<<<eBlocks, 256, 0, stream>>>(row, col, rowptr, cursor, srcs, E);
    pad_kernel<<<nBlocks, 256, 0, stream>>>(deg, rowptr, srcs, N);
    wcvt_kernel<<<(15 * 4096 + 255) / 256, 256, 0, stream>>>(w1, w2, wf);
    zero_pads_kernel<<<(NBUF * 64 + 255) / 256, 256, 0, stream>>>(gbase, gstride, NBUF, N);
    cvt_g_kernel<<<xBlocks, 256, 0, stream>>>(x, dinv, G(0), N);

    // ---- layer 1: 10 pure-gather hops: G(k-1) -> G(k) ----
    for (int k = 1; k <= K1; ++k)
        hop_kernel<<<gBlocks, 256, 0, stream>>>(G(k - 1), srcs, rowptr, dinv2, G(k), N);

    // ---- layer-1 GEMMs + tanh + next-layer g:  g2_0 = G(1) (row-disjoint overwrite) ----
    final_kernel<<<gBlocks, 256, 0, stream>>>(gbase, gstride, 11, wf, sdeg, b1, dinv,
                                              G(1), nullptr, 0, ntiles);

    // ---- layer 2: 3 hops: G(1)->G(2)->G(3)->G(4) ----
    for (int k = 1; k <= K2; ++k)
        hop_kernel<<<gBlocks, 256, 0, stream>>>(G(k), srcs, rowptr, dinv2, G(k + 1), N);

    // ---- layer-2 GEMMs + tanh -> v (fp32) ----
    final_kernel<<<gBlocks, 256, 0, stream>>>(G(1), gstride, 4, wf + (size_t)11 * 4096,
                                              sdeg, b2, dinv, nullptr, vbuf, 1, ntiles);

    // ---- head: out = v @ wc + bc ----
    gemm_bias_kernel<<<gBlocks, 256, 0, stream>>>(vbuf, wc, bc, out, N);
}

// Round 7
// 719.819 us; speedup vs baseline: 2.7318x; 1.1489x over previous
//
#include <hip/hip_runtime.h>
#include <hip/hip_bf16.h>

#define PAD 16        // pad each CSR segment to a multiple of 16 edges
#define NBKT_MAX 512  // buckets of 512 dests (dest >> 9)

typedef __attribute__((ext_vector_type(8))) short short8;
typedef __attribute__((ext_vector_type(4))) float float4v;

__device__ __forceinline__ short8 as_s8(uint4 v) {
    union { uint4 u; short8 s; } x; x.u = v; return x.s;
}

// ---------------- graph preprocessing ----------------

__global__ void deg_kernel(const int* __restrict__ col, int* __restrict__ deg, int E) {
    int e = blockIdx.x * blockDim.x + threadIdx.x;
    if (e < E) atomicAdd(&deg[col[e]], 1);
}

__global__ void dinv_kernel(const int* __restrict__ deg, float* __restrict__ dinv,
                            float* __restrict__ dinv2, float* __restrict__ sdeg, int N) {
    int n = blockIdx.x * blockDim.x + threadIdx.x;
    if (n < N) {
        int d = deg[n];
        float v = d > 0 ? rsqrtf((float)d) : 0.0f;
        dinv[n] = v;
        dinv2[n] = v * v;
        sdeg[n] = d > 0 ? sqrtf((float)d) : 0.0f;
    }
}

__device__ __forceinline__ int pad_up(int v) { return (v + (PAD - 1)) & ~(PAD - 1); }

// 3-phase exclusive scan over padded deg -> rowptr[N+1], chunk = 512
__global__ void scan_phaseA(const int* __restrict__ deg, int* __restrict__ chunkSum, int N) {
    int t = threadIdx.x;
    int idx = blockIdx.x * 512 + t;
    int v = idx < N ? pad_up(deg[idx]) : 0;
    for (int o = 32; o > 0; o >>= 1) v += __shfl_down(v, o, 64);
    __shared__ int wsum[8];
    if ((t & 63) == 0) wsum[t >> 6] = v;
    __syncthreads();
    if (t == 0) {
        int s = 0;
        for (int i = 0; i < 8; ++i) s += wsum[i];
        chunkSum[blockIdx.x] = s;
    }
}

// generic single-block exclusive scan over n<=256 ints
__global__ void scan_phaseB(const int* __restrict__ in, int* __restrict__ outp, int n) {
    __shared__ int a[256], b[256];
    int t = threadIdx.x;
    int v = t < n ? in[t] : 0;
    a[t] = v;
    __syncthreads();
    int* s = a; int* d = b;
    for (int off = 1; off < 256; off <<= 1) {
        int x = s[t];
        if (t >= off) x += s[t - off];
        d[t] = x;
        __syncthreads();
        int* tmp = s; s = d; d = tmp;
    }
    if (t < n) outp[t] = s[t] - v;
}

__global__ void scan_phaseC(const int* __restrict__ deg, const int* __restrict__ chunkOff,
                            int* __restrict__ rowptr, int N) {
    __shared__ int a[512], b[512];
    int t = threadIdx.x;
    int idx = blockIdx.x * 512 + t;
    int v = idx < N ? pad_up(deg[idx]) : 0;
    a[t] = v;
    __syncthreads();
    int* s = a; int* d = b;
    for (int off = 1; off < 512; off <<= 1) {
        int x = s[t];
        if (t >= off) x += s[t - off];
        d[t] = x;
        __syncthreads();
        int* tmp = s; s = d; d = tmp;
    }
    if (idx < N) rowptr[idx] = chunkOff[blockIdx.x] + s[t] - v;
    if (idx == N - 1) rowptr[N] = chunkOff[blockIdx.x] + s[t];
}

// ---- bucketed CSR build (replaces random 4B scatter fill) ----

// per-block histogram of dest buckets; blockHist[bucket][block]
__global__ __launch_bounds__(256) void hist_kernel(const int* __restrict__ col,
                                                   int* __restrict__ blockHist, int E, int nbkt) {
    __shared__ int h[NBKT_MAX];
    for (int i = threadIdx.x; i < nbkt; i += 256) h[i] = 0;
    __syncthreads();
    int chunk = (E + gridDim.x - 1) / gridDim.x;
    int lo = blockIdx.x * chunk, hi = min(lo + chunk, E);
    for (int e = lo + threadIdx.x; e < hi; e += 256) atomicAdd(&h[col[e] >> 9], 1);
    __syncthreads();
    for (int i = threadIdx.x; i < nbkt; i += 256) blockHist[i * 256 + blockIdx.x] = h[i];
}

// per-bucket exclusive scan across the 256 blocks; bktTot[bucket] = total
__global__ __launch_bounds__(256) void bscan_kernel(int* __restrict__ blockHist,
                                                    int* __restrict__ bktTot, int nbkt) {
    __shared__ int a[256], b[256];
    int bkt = blockIdx.x;
    int t = threadIdx.x;
    int v = blockHist[bkt * 256 + t];
    a[t] = v;
    __syncthreads();
    int* s = a; int* d = b;
    for (int off = 1; off < 256; off <<= 1) {
        int x = s[t];
        if (t >= off) x += s[t - off];
        d[t] = x;
        __syncthreads();
        int* tmp = s; s = d; d = tmp;
    }
    blockHist[bkt * 256 + t] = s[t] - v;
    if (t == 255) bktTot[bkt] = s[t];
}

// scatter (src,dest) pairs into bucket-grouped array; per-(block,bucket) runs contiguous
__global__ __launch_bounds__(256) void scatter_kernel(const int* __restrict__ row,
                                                      const int* __restrict__ col,
                                                      const int* __restrict__ blockHist,
                                                      const int* __restrict__ bktOff,
                                                      int2* __restrict__ pairs, int E, int nbkt) {
    __shared__ int cur[NBKT_MAX];
    for (int i = threadIdx.x; i < nbkt; i += 256)
        cur[i] = bktOff[i] + blockHist[i * 256 + blockIdx.x];
    __syncthreads();
    int chunk = (E + gridDim.x - 1) / gridDim.x;
    int lo = blockIdx.x * chunk, hi = min(lo + chunk, E);
    for (int e = lo + threadIdx.x; e < hi; e += 256) {
        int dn = col[e];
        int p = atomicAdd(&cur[dn >> 9], 1);
        pairs[p] = make_int2(row[e], dn);
    }
}

// per-bucket: scatter srcs into the bucket's contiguous CSR window (L2-resident)
__global__ __launch_bounds__(256) void cluster_kernel(const int2* __restrict__ pairs,
                                                      const int* __restrict__ bktOff,
                                                      const int* __restrict__ bktTot,
                                                      const int* __restrict__ rowptr,
                                                      int* __restrict__ srcs, int N) {
    __shared__ int cur[512];
    int b = blockIdx.x;
    int d0 = b << 9;
    for (int i = threadIdx.x; i < 512; i += 256) {
        int d = d0 + i;
        cur[i] = (d < N) ? rowptr[d] : 0;
    }
    __syncthreads();
    int lo = bktOff[b], hi = lo + bktTot[b];
    for (int p = lo + threadIdx.x; p < hi; p += 256) {
        int2 e = pairs[p];
        int pos = atomicAdd(&cur[e.y - d0], 1);
        srcs[pos] = e.x;
    }
}

__global__ void pad_kernel(const int* __restrict__ deg, const int* __restrict__ rowptr,
                           int* __restrict__ srcs, int N) {
    int dn = blockIdx.x * blockDim.x + threadIdx.x;
    if (dn < N) {
        int p = rowptr[dn] + deg[dn];
        int p1 = rowptr[dn + 1];
        for (; p < p1; ++p) srcs[p] = N;
    }
}

// Convert w1 (11) + w2 (4) + wc (1) into MFMA B-fragment order, bf16.
// wf[g][((t*4+u)*64 + lane)*8 + j] = bf16(W_g[k][n]), k=t*32+(lane>>4)*8+j, n=u*16+(lane&15)
__global__ void wcvt_kernel(const float* __restrict__ w1, const float* __restrict__ w2,
                            const float* __restrict__ wc, __hip_bfloat16* __restrict__ wf) {
    int idx = blockIdx.x * blockDim.x + threadIdx.x;
    if (idx >= 16 * 4096) return;
    int g = idx >> 12, r = idx & 4095;
    int j = r & 7, lane = (r >> 3) & 63, u = (r >> 9) & 3, t = r >> 11;
    int k = t * 32 + (lane >> 4) * 8 + j;
    int n = u * 16 + (lane & 15);
    const float* W = (g < 11) ? (w1 + (size_t)g * 4096)
                  : (g < 15) ? (w2 + (size_t)(g - 11) * 4096) : wc;
    wf[idx] = __float2bfloat16(W[k * 64 + n]);
}

// zero pad row N of all nbuf g buffers
__global__ void zero_pads_kernel(__hip_bfloat16* __restrict__ gbase, size_t gstride,
                                 int nbuf, int N) {
    int i = blockIdx.x * blockDim.x + threadIdx.x;
    int b = i >> 6;
    if (b < nbuf) gbase[(size_t)b * gstride + (size_t)N * 64 + (i & 63)] = __float2bfloat16(0.0f);
}

// g0 = bf16(dinv ⊙ x)
__global__ void cvt_g_kernel(const float* __restrict__ x, const float* __restrict__ dinv,
                             __hip_bfloat16* __restrict__ g, int N) {
    int i = blockIdx.x * blockDim.x + threadIdx.x;
    if (i < N * 64) g[i] = __float2bfloat16(dinv[i >> 6] * x[i]);
}

// ---------------- propagation: pure gather hop ----------------

__global__ __launch_bounds__(256) void hop_kernel(
        const __hip_bfloat16* __restrict__ g_in,
        const int* __restrict__ srcs, const int* __restrict__ rowptr,
        const float* __restrict__ dinv2,
        __hip_bfloat16* __restrict__ g_out, int n) {
    const int lane = threadIdx.x & 63;
    int gw = __builtin_amdgcn_readfirstlane((blockIdx.x * blockDim.x + threadIdx.x) >> 6);
    int nw = (gridDim.x * blockDim.x) >> 6;
    for (int d = gw; d < n; d += nw) {
        int p0 = rowptr[d], p1 = rowptr[d + 1];
        float agg = 0.f;
        for (int p = p0; p < p1; p += 16) {
            int s0  = srcs[p + 0],  s1  = srcs[p + 1],  s2  = srcs[p + 2],  s3  = srcs[p + 3];
            int s4  = srcs[p + 4],  s5  = srcs[p + 5],  s6  = srcs[p + 6],  s7  = srcs[p + 7];
            int s8  = srcs[p + 8],  s9  = srcs[p + 9],  s10 = srcs[p + 10], s11 = srcs[p + 11];
            int s12 = srcs[p + 12], s13 = srcs[p + 13], s14 = srcs[p + 14], s15 = srcs[p + 15];
            float v0  = __bfloat162float(g_in[(size_t)s0  * 64 + lane]);
            float v1  = __bfloat162float(g_in[(size_t)s1  * 64 + lane]);
            float v2  = __bfloat162float(g_in[(size_t)s2  * 64 + lane]);
            float v3  = __bfloat162float(g_in[(size_t)s3  * 64 + lane]);
            float v4  = __bfloat162float(g_in[(size_t)s4  * 64 + lane]);
            float v5  = __bfloat162float(g_in[(size_t)s5  * 64 + lane]);
            float v6  = __bfloat162float(g_in[(size_t)s6  * 64 + lane]);
            float v7  = __bfloat162float(g_in[(size_t)s7  * 64 + lane]);
            float v8  = __bfloat162float(g_in[(size_t)s8  * 64 + lane]);
            float v9  = __bfloat162float(g_in[(size_t)s9  * 64 + lane]);
            float v10 = __bfloat162float(g_in[(size_t)s10 * 64 + lane]);
            float v11 = __bfloat162float(g_in[(size_t)s11 * 64 + lane]);
            float v12 = __bfloat162float(g_in[(size_t)s12 * 64 + lane]);
            float v13 = __bfloat162float(g_in[(size_t)s13 * 64 + lane]);
            float v14 = __bfloat162float(g_in[(size_t)s14 * 64 + lane]);
            float v15 = __bfloat162float(g_in[(size_t)s15 * 64 + lane]);
            agg += v0;  agg += v1;  agg += v2;  agg += v3;
            agg += v4;  agg += v5;  agg += v6;  agg += v7;
            agg += v8;  agg += v9;  agg += v10; agg += v11;
            agg += v12; agg += v13; agg += v14; agg += v15;
        }
        g_out[(size_t)d * 64 + lane] = __float2bfloat16(dinv2[d] * agg);
    }
}

// ---------------- deferred multi-GEMM (MFMA) ----------------
// acc = sum_g G_g @ W_g ; tv = tanh(sdeg*acc + bias)
// out16 = bf16(scale * tv), scale = dinv (layer boundary) or 1 (pre-head v)

__global__ __launch_bounds__(256) void final_kernel(
        const __hip_bfloat16* gbase, size_t gstride, int ngemm,
        const __hip_bfloat16* __restrict__ wf,
        const float* __restrict__ sdeg, const float* __restrict__ bias,
        const float* __restrict__ scale,
        __hip_bfloat16* out16, int ntiles) {
    const int lane = threadIdx.x & 63;
    const int col = lane & 15, quad = lane >> 4;
    int wv = (blockIdx.x * blockDim.x + threadIdx.x) >> 6;
    int nwv = (gridDim.x * blockDim.x) >> 6;
    const uint4* wfq = (const uint4*)wf;
    for (int tile = wv; tile < ntiles; tile += nwv) {
        int base = tile * 16;
        float4v acc0 = {0.f, 0.f, 0.f, 0.f};
        float4v acc1 = {0.f, 0.f, 0.f, 0.f};
        float4v acc2 = {0.f, 0.f, 0.f, 0.f};
        float4v acc3 = {0.f, 0.f, 0.f, 0.f};
        for (int g = 0; g < ngemm; ++g) {
            const uint4* ga = (const uint4*)(gbase + (size_t)g * gstride);
            const uint4* wg = wfq + (size_t)g * 512;
#pragma unroll
            for (int t = 0; t < 2; ++t) {
                short8 a = as_s8(ga[(size_t)(base + col) * 8 + t * 4 + quad]);
                short8 b0 = as_s8(wg[(t * 4 + 0) * 64 + lane]);
                short8 b1 = as_s8(wg[(t * 4 + 1) * 64 + lane]);
                short8 b2 = as_s8(wg[(t * 4 + 2) * 64 + lane]);
                short8 b3 = as_s8(wg[(t * 4 + 3) * 64 + lane]);
                acc0 = __builtin_amdgcn_mfma_f32_16x16x32_bf16(a, b0, acc0, 0, 0, 0);
                acc1 = __builtin_amdgcn_mfma_f32_16x16x32_bf16(a, b1, acc1, 0, 0, 0);
                acc2 = __builtin_amdgcn_mfma_f32_16x16x32_bf16(a, b2, acc2, 0, 0, 0);
                acc3 = __builtin_amdgcn_mfma_f32_16x16x32_bf16(a, b3, acc3, 0, 0, 0);
            }
        }
#pragma unroll
        for (int r = 0; r < 4; ++r) {
            int nd = base + quad * 4 + r;
            float sd = sdeg[nd];
            float sc = scale ? scale[nd] : 1.0f;
            float f0 = sc * tanhf(sd * acc0[r] + bias[0 * 16 + col]);
            float f1 = sc * tanhf(sd * acc1[r] + bias[1 * 16 + col]);
            float f2 = sc * tanhf(sd * acc2[r] + bias[2 * 16 + col]);
            float f3 = sc * tanhf(sd * acc3[r] + bias[3 * 16 + col]);
            out16[(size_t)nd * 64 + 0 * 16 + col] = __float2bfloat16(f0);
            out16[(size_t)nd * 64 + 1 * 16 + col] = __float2bfloat16(f1);
            out16[(size_t)nd * 64 + 2 * 16 + col] = __float2bfloat16(f2);
            out16[(size_t)nd * 64 + 3 * 16 + col] = __float2bfloat16(f3);
        }
    }
}

// ---------------- MFMA head: out = v16 @ Wc + bc ----------------

__global__ __launch_bounds__(256) void head_kernel(
        const __hip_bfloat16* __restrict__ v16, const __hip_bfloat16* __restrict__ wfc,
        const float* __restrict__ bc, float* __restrict__ out, int ntiles) {
    const int lane = threadIdx.x & 63;
    const int col = lane & 15, quad = lane >> 4;
    int wv = (blockIdx.x * blockDim.x + threadIdx.x) >> 6;
    int nwv = (gridDim.x * blockDim.x) >> 6;
    const uint4* va = (const uint4*)v16;
    const uint4* wg = (const uint4*)wfc;
    for (int tile = wv; tile < ntiles; tile += nwv) {
        int base = tile * 16;
        float4v acc0 = {0.f, 0.f, 0.f, 0.f};
        float4v acc1 = {0.f, 0.f, 0.f, 0.f};
        float4v acc2 = {0.f, 0.f, 0.f, 0.f};
        float4v acc3 = {0.f, 0.f, 0.f, 0.f};
#pragma unroll
        for (int t = 0; t < 2; ++t) {
            short8 a = as_s8(va[(size_t)(base + col) * 8 + t * 4 + quad]);
            short8 b0 = as_s8(wg[(t * 4 + 0) * 64 + lane]);
            short8 b1 = as_s8(wg[(t * 4 + 1) * 64 + lane]);
            short8 b2 = as_s8(wg[(t * 4 + 2) * 64 + lane]);
            short8 b3 = as_s8(wg[(t * 4 + 3) * 64 + lane]);
            acc0 = __builtin_amdgcn_mfma_f32_16x16x32_bf16(a, b0, acc0, 0, 0, 0);
            acc1 = __builtin_amdgcn_mfma_f32_16x16x32_bf16(a, b1, acc1, 0, 0, 0);
            acc2 = __builtin_amdgcn_mfma_f32_16x16x32_bf16(a, b2, acc2, 0, 0, 0);
            acc3 = __builtin_amdgcn_mfma_f32_16x16x32_bf16(a, b3, acc3, 0, 0, 0);
        }
#pragma unroll
        for (int r = 0; r < 4; ++r) {
            int nd = base + quad * 4 + r;
            out[(size_t)nd * 64 + 0 * 16 + col] = acc0[r] + bc[0 * 16 + col];
            out[(size_t)nd * 64 + 1 * 16 + col] = acc1[r] + bc[1 * 16 + col];
            out[(size_t)nd * 64 + 2 * 16 + col] = acc2[r] + bc[2 * 16 + col];
            out[(size_t)nd * 64 + 3 * 16 + col] = acc3[r] + bc[3 * 16 + col];
        }
    }
}

// ---------------- launch ----------------

extern "C" void kernel_launch(void* const* d_in, const int* in_sizes, int n_in,
                              void* d_out, int out_size, void* d_ws, size_t ws_size,
                              hipStream_t stream) {
    const float* x  = (const float*)d_in[0];
    const int*   ei = (const int*)d_in[1];   // [2, E] int32
    const float* w1 = (const float*)d_in[2]; // [11,64,64]
    const float* b1 = (const float*)d_in[3];
    const float* w2 = (const float*)d_in[4]; // [4,64,64]
    const float* b2 = (const float*)d_in[5];
    const float* wc = (const float*)d_in[6];
    const float* bc = (const float*)d_in[7];
    float* out = (float*)d_out;

    const int N = in_sizes[0] / 64;
    const int E = in_sizes[1] / 2;
    const int K1 = 10, K2 = 3;
    const int* row = ei;
    const int* col = ei + E;
    const int Epad = E + (PAD - 1) * N + 64;
    const int NBUF = 11;
    const int nbkt = (N + 511) >> 9;
    const size_t gstride = (((size_t)(N + 1) * 64) + 127) & ~(size_t)127;

    // workspace carve (256B aligned)
    char* base = (char*)d_ws;
    auto alloc = [&](size_t bytes) { void* p = (void*)base; base += (bytes + 255) & ~(size_t)255; return p; };
    int*   deg      = (int*)alloc((size_t)N * 4);
    int*   rowptr   = (int*)alloc((size_t)(N + 1) * 4);
    int*   chunkSum = (int*)alloc(256 * 4);
    int*   chunkOff = (int*)alloc(256 * 4);
    int*   blockHist= (int*)alloc((size_t)NBKT_MAX * 256 * 4);
    int*   bktTot   = (int*)alloc((size_t)NBKT_MAX * 4);
    int*   bktOff   = (int*)alloc((size_t)NBKT_MAX * 4);
    float* dinv     = (float*)alloc((size_t)N * 4);
    float* dinv2    = (float*)alloc((size_t)N * 4);
    float* sdeg     = (float*)alloc((size_t)N * 4);
    int*   srcs     = (int*)alloc((size_t)Epad * 4);
    __hip_bfloat16* wf    = (__hip_bfloat16*)alloc((size_t)16 * 4096 * 2);
    __hip_bfloat16* gbase = (__hip_bfloat16*)alloc((size_t)NBUF * gstride * 2);

    auto G = [&](int k) { return gbase + (size_t)k * gstride; };
    int2* pairs = (int2*)G(9);            // dead until hop 9; consumed by cluster first
    __hip_bfloat16* vbuf16 = G(5);        // free during layer-2 (hops use G(1..4))

    const int numChunks = (N + 511) / 512;
    const int eBlocks = (E + 255) / 256;
    const int nBlocks = (N + 255) / 256;
    const int xBlocks = (N * 64 + 255) / 256;
    const int gBlocks = 2048;
    const int ntiles = (N + 15) / 16;

    // ---- graph preprocessing ----
    hipMemsetAsync(deg, 0, (size_t)N * 4, stream);
    deg_kernel<<<eBlocks, 256, 0, stream>>>(col, deg, E);
    dinv_kernel<<<nBlocks, 256, 0, stream>>>(deg, dinv, dinv2, sdeg, N);
    scan_phaseA<<<numChunks, 512, 0, stream>>>(deg, chunkSum, N);
    scan_phaseB<<<1, 256, 0, stream>>>(chunkSum, chunkOff, numChunks);
    scan_phaseC<<<numChunks, 512, 0, stream>>>(deg, chunkOff, rowptr, N);

    hist_kernel<<<256, 256, 0, stream>>>(col, blockHist, E, nbkt);
    bscan_kernel<<<nbkt, 256, 0, stream>>>(blockHist, bktTot, nbkt);
    scan_phaseB<<<1, 256, 0, stream>>>(bktTot, bktOff, nbkt);
    scatter_kernel<<<256, 256, 0, stream>>>(row, col, blockHist, bktOff, pairs, E, nbkt);
    cluster_kernel<<<nbkt, 256, 0, stream>>>(pairs, bktOff, bktTot, rowptr, srcs, N);
    pad_kernel<<<nBlocks, 256, 0, stream>>>(deg, rowptr, srcs, N);

    wcvt_kernel<<<(16 * 4096 + 255) / 256, 256, 0, stream>>>(w1, w2, wc, wf);
    zero_pads_kernel<<<(NBUF * 64 + 255) / 256, 256, 0, stream>>>(gbase, gstride, NBUF, N);
    cvt_g_kernel<<<xBlocks, 256, 0, stream>>>(x, dinv, G(0), N);

    // ---- layer 1: 10 pure-gather hops: G(k-1) -> G(k) ----
    for (int k = 1; k <= K1; ++k)
        hop_kernel<<<gBlocks, 256, 0, stream>>>(G(k - 1), srcs, rowptr, dinv2, G(k), N);

    // ---- layer-1 GEMMs + tanh + next-layer g -> G(1) (tile-local overwrite: safe) ----
    final_kernel<<<gBlocks, 256, 0, stream>>>(gbase, gstride, 11, wf, sdeg, b1, dinv,
                                              G(1), ntiles);

    // ---- layer 2: 3 hops: G(1)->G(2)->G(3)->G(4) ----
    for (int k = 1; k <= K2; ++k)
        hop_kernel<<<gBlocks, 256, 0, stream>>>(G(k), srcs, rowptr, dinv2, G(k + 1), N);

    // ---- layer-2 GEMMs + tanh -> v16 (bf16) ----
    final_kernel<<<gBlocks, 256, 0, stream>>>(G(1), gstride, 4, wf + (size_t)11 * 4096,
                                              sdeg, b2, nullptr, vbuf16, ntiles);

    // ---- MFMA head: out = v16 @ wc + bc ----
    head_kernel<<<gBlocks, 256, 0, stream>>>(vbuf16, wf + (size_t)15 * 4096, bc, out, ntiles);
}

// Round 8
// 657.581 us; speedup vs baseline: 2.9904x; 1.0946x over previous
//
#include <hip/hip_runtime.h>
#include <hip/hip_bf16.h>

#define PAD 16        // pad each CSR segment to a multiple of 16 edges
#define NBKT_MAX 512  // buckets of 512 dests (dest >> 9)

typedef __attribute__((ext_vector_type(8))) short short8;
typedef __attribute__((ext_vector_type(4))) float float4v;

__device__ __forceinline__ short8 as_s8(uint4 v) {
    union { uint4 u; short8 s; } x; x.u = v; return x.s;
}

__device__ __forceinline__ int pad_up(int v) { return (v + (PAD - 1)) & ~(PAD - 1); }

// ---------------- bucketed CSR build ----------------

// per-block histogram of dest buckets; blockHist[bucket][block]
__global__ __launch_bounds__(256) void hist_kernel(const int* __restrict__ col,
                                                   int* __restrict__ blockHist, int E, int nbkt) {
    __shared__ int h[NBKT_MAX];
    for (int i = threadIdx.x; i < nbkt; i += 256) h[i] = 0;
    __syncthreads();
    int chunk = (E + gridDim.x - 1) / gridDim.x;
    int lo = blockIdx.x * chunk, hi = min(lo + chunk, E);
    for (int e = lo + threadIdx.x; e < hi; e += 256) atomicAdd(&h[col[e] >> 9], 1);
    __syncthreads();
    for (int i = threadIdx.x; i < nbkt; i += 256) blockHist[i * 256 + blockIdx.x] = h[i];
}

// per-bucket exclusive scan across the 256 blocks; bktTot[bucket] = total
__global__ __launch_bounds__(256) void bscan_kernel(int* __restrict__ blockHist,
                                                    int* __restrict__ bktTot, int nbkt) {
    __shared__ int a[256], b[256];
    int bkt = blockIdx.x;
    int t = threadIdx.x;
    int v = blockHist[bkt * 256 + t];
    a[t] = v;
    __syncthreads();
    int* s = a; int* d = b;
    for (int off = 1; off < 256; off <<= 1) {
        int x = s[t];
        if (t >= off) x += s[t - off];
        d[t] = x;
        __syncthreads();
        int* tmp = s; s = d; d = tmp;
    }
    blockHist[bkt * 256 + t] = s[t] - v;
    if (t == 255) bktTot[bkt] = s[t];
}

// generic single-block exclusive scan over n<=256 ints
__global__ void scan_small(const int* __restrict__ in, int* __restrict__ outp, int n) {
    __shared__ int a[256], b[256];
    int t = threadIdx.x;
    int v = t < n ? in[t] : 0;
    a[t] = v;
    __syncthreads();
    int* s = a; int* d = b;
    for (int off = 1; off < 256; off <<= 1) {
        int x = s[t];
        if (t >= off) x += s[t - off];
        d[t] = x;
        __syncthreads();
        int* tmp = s; s = d; d = tmp;
    }
    if (t < n) outp[t] = s[t] - v;
}

// scatter (src,dest) pairs into bucket-grouped array; per-(block,bucket) runs contiguous
__global__ __launch_bounds__(256) void scatter_kernel(const int* __restrict__ row,
                                                      const int* __restrict__ col,
                                                      const int* __restrict__ blockHist,
                                                      const int* __restrict__ bktOff,
                                                      int2* __restrict__ pairs, int E, int nbkt) {
    __shared__ int cur[NBKT_MAX];
    for (int i = threadIdx.x; i < nbkt; i += 256)
        cur[i] = bktOff[i] + blockHist[i * 256 + blockIdx.x];
    __syncthreads();
    int chunk = (E + gridDim.x - 1) / gridDim.x;
    int lo = blockIdx.x * chunk, hi = min(lo + chunk, E);
    for (int e = lo + threadIdx.x; e < hi; e += 256) {
        int dn = col[e];
        int p = atomicAdd(&cur[dn >> 9], 1);
        pairs[p] = make_int2(row[e], dn);
    }
}

// per-bucket LDS degree histogram -> deg/dinv/dinv2/sdeg (coalesced writes)
__global__ __launch_bounds__(256) void deg_pairs_kernel(
        const int2* __restrict__ pairs, const int* __restrict__ bktOff,
        const int* __restrict__ bktTot,
        int* __restrict__ deg, float* __restrict__ dinv, float* __restrict__ dinv2,
        float* __restrict__ sdeg, int N) {
    __shared__ int cnt[512];
    int b = blockIdx.x, d0 = b << 9;
    for (int i = threadIdx.x; i < 512; i += 256) cnt[i] = 0;
    __syncthreads();
    int lo = bktOff[b], hi = lo + bktTot[b];
    for (int p = lo + threadIdx.x; p < hi; p += 256)
        atomicAdd(&cnt[pairs[p].y - d0], 1);
    __syncthreads();
    for (int i = threadIdx.x; i < 512; i += 256) {
        int d = d0 + i;
        if (d < N) {
            int c = cnt[i];
            deg[d] = c;
            float v = c > 0 ? rsqrtf((float)c) : 0.0f;
            dinv[d] = v;
            dinv2[d] = v * v;
            sdeg[d] = c > 0 ? sqrtf((float)c) : 0.0f;
        }
    }
}

// 3-phase exclusive scan over padded deg -> rowptr[N+1], chunk = 512
__global__ void scan_phaseA(const int* __restrict__ deg, int* __restrict__ chunkSum, int N) {
    int t = threadIdx.x;
    int idx = blockIdx.x * 512 + t;
    int v = idx < N ? pad_up(deg[idx]) : 0;
    for (int o = 32; o > 0; o >>= 1) v += __shfl_down(v, o, 64);
    __shared__ int wsum[8];
    if ((t & 63) == 0) wsum[t >> 6] = v;
    __syncthreads();
    if (t == 0) {
        int s = 0;
        for (int i = 0; i < 8; ++i) s += wsum[i];
        chunkSum[blockIdx.x] = s;
    }
}

__global__ void scan_phaseC(const int* __restrict__ deg, const int* __restrict__ chunkOff,
                            int* __restrict__ rowptr, int N) {
    __shared__ int a[512], b[512];
    int t = threadIdx.x;
    int idx = blockIdx.x * 512 + t;
    int v = idx < N ? pad_up(deg[idx]) : 0;
    a[t] = v;
    __syncthreads();
    int* s = a; int* d = b;
    for (int off = 1; off < 512; off <<= 1) {
        int x = s[t];
        if (t >= off) x += s[t - off];
        d[t] = x;
        __syncthreads();
        int* tmp = s; s = d; d = tmp;
    }
    if (idx < N) rowptr[idx] = chunkOff[blockIdx.x] + s[t] - v;
    if (idx == N - 1) rowptr[N] = chunkOff[blockIdx.x] + s[t];
}

// per-bucket: scatter srcs into the bucket's contiguous CSR window (L2-resident),
// then fill pad slots (cur[i] -> rowptr[d+1]) while the window is hot.
__global__ __launch_bounds__(256) void cluster_kernel(const int2* __restrict__ pairs,
                                                      const int* __restrict__ bktOff,
                                                      const int* __restrict__ bktTot,
                                                      const int* __restrict__ rowptr,
                                                      int* __restrict__ srcs, int N) {
    __shared__ int cur[512];
    int b = blockIdx.x;
    int d0 = b << 9;
    for (int i = threadIdx.x; i < 512; i += 256) {
        int d = d0 + i;
        cur[i] = (d < N) ? rowptr[d] : 0;
    }
    __syncthreads();
    int lo = bktOff[b], hi = lo + bktTot[b];
    for (int p = lo + threadIdx.x; p < hi; p += 256) {
        int2 e = pairs[p];
        int pos = atomicAdd(&cur[e.y - d0], 1);
        srcs[pos] = e.x;
    }
    __syncthreads();
    for (int i = threadIdx.x; i < 512; i += 256) {
        int d = d0 + i;
        if (d < N) {
            int p = cur[i];              // == rowptr[d] + deg[d]
            int p1 = rowptr[d + 1];
            for (; p < p1; ++p) srcs[p] = N;
        }
    }
}

// ---------------- weight conversion / g init ----------------

// Convert w1 (11) + w2 (4) + wc (1) into MFMA B-fragment order, bf16.
__global__ void wcvt_kernel(const float* __restrict__ w1, const float* __restrict__ w2,
                            const float* __restrict__ wc, __hip_bfloat16* __restrict__ wf) {
    int idx = blockIdx.x * blockDim.x + threadIdx.x;
    if (idx >= 16 * 4096) return;
    int g = idx >> 12, r = idx & 4095;
    int j = r & 7, lane = (r >> 3) & 63, u = (r >> 9) & 3, t = r >> 11;
    int k = t * 32 + (lane >> 4) * 8 + j;
    int n = u * 16 + (lane & 15);
    const float* W = (g < 11) ? (w1 + (size_t)g * 4096)
                  : (g < 15) ? (w2 + (size_t)(g - 11) * 4096) : wc;
    wf[idx] = __float2bfloat16(W[k * 64 + n]);
}

// zero pad row N of all nbuf g buffers
__global__ void zero_pads_kernel(__hip_bfloat16* __restrict__ gbase, size_t gstride,
                                 int nbuf, int N) {
    int i = blockIdx.x * blockDim.x + threadIdx.x;
    int b = i >> 6;
    if (b < nbuf) gbase[(size_t)b * gstride + (size_t)N * 64 + (i & 63)] = __float2bfloat16(0.0f);
}

// g0 = bf16(dinv ⊙ x)
__global__ void cvt_g_kernel(const float* __restrict__ x, const float* __restrict__ dinv,
                             __hip_bfloat16* __restrict__ g, int N) {
    int i = blockIdx.x * blockDim.x + threadIdx.x;
    if (i < N * 64) g[i] = __float2bfloat16(dinv[i >> 6] * x[i]);
}

// ---------------- propagation: pure gather hop ----------------

__global__ __launch_bounds__(256) void hop_kernel(
        const __hip_bfloat16* __restrict__ g_in,
        const int* __restrict__ srcs, const int* __restrict__ rowptr,
        const float* __restrict__ dinv2,
        __hip_bfloat16* __restrict__ g_out, int n) {
    const int lane = threadIdx.x & 63;
    int gw = __builtin_amdgcn_readfirstlane((blockIdx.x * blockDim.x + threadIdx.x) >> 6);
    int nw = (gridDim.x * blockDim.x) >> 6;
    for (int d = gw; d < n; d += nw) {
        int p0 = rowptr[d], p1 = rowptr[d + 1];
        float agg = 0.f;
        for (int p = p0; p < p1; p += 16) {
            int s0  = srcs[p + 0],  s1  = srcs[p + 1],  s2  = srcs[p + 2],  s3  = srcs[p + 3];
            int s4  = srcs[p + 4],  s5  = srcs[p + 5],  s6  = srcs[p + 6],  s7  = srcs[p + 7];
            int s8  = srcs[p + 8],  s9  = srcs[p + 9],  s10 = srcs[p + 10], s11 = srcs[p + 11];
            int s12 = srcs[p + 12], s13 = srcs[p + 13], s14 = srcs[p + 14], s15 = srcs[p + 15];
            float v0  = __bfloat162float(g_in[(size_t)s0  * 64 + lane]);
            float v1  = __bfloat162float(g_in[(size_t)s1  * 64 + lane]);
            float v2  = __bfloat162float(g_in[(size_t)s2  * 64 + lane]);
            float v3  = __bfloat162float(g_in[(size_t)s3  * 64 + lane]);
            float v4  = __bfloat162float(g_in[(size_t)s4  * 64 + lane]);
            float v5  = __bfloat162float(g_in[(size_t)s5  * 64 + lane]);
            float v6  = __bfloat162float(g_in[(size_t)s6  * 64 + lane]);
            float v7  = __bfloat162float(g_in[(size_t)s7  * 64 + lane]);
            float v8  = __bfloat162float(g_in[(size_t)s8  * 64 + lane]);
            float v9  = __bfloat162float(g_in[(size_t)s9  * 64 + lane]);
            float v10 = __bfloat162float(g_in[(size_t)s10 * 64 + lane]);
            float v11 = __bfloat162float(g_in[(size_t)s11 * 64 + lane]);
            float v12 = __bfloat162float(g_in[(size_t)s12 * 64 + lane]);
            float v13 = __bfloat162float(g_in[(size_t)s13 * 64 + lane]);
            float v14 = __bfloat162float(g_in[(size_t)s14 * 64 + lane]);
            float v15 = __bfloat162float(g_in[(size_t)s15 * 64 + lane]);
            agg += v0;  agg += v1;  agg += v2;  agg += v3;
            agg += v4;  agg += v5;  agg += v6;  agg += v7;
            agg += v8;  agg += v9;  agg += v10; agg += v11;
            agg += v12; agg += v13; agg += v14; agg += v15;
        }
        g_out[(size_t)d * 64 + lane] = __float2bfloat16(dinv2[d] * agg);
    }
}

// ---------------- deferred multi-GEMM (MFMA) ----------------
// acc = sum_g G_g @ W_g ; tv = tanh(sdeg*acc + bias)
// out16 = bf16(scale * tv), scale = dinv (layer boundary) or 1 (pre-head v)

__global__ __launch_bounds__(256) void final_kernel(
        const __hip_bfloat16* gbase, size_t gstride, int ngemm,
        const __hip_bfloat16* __restrict__ wf,
        const float* __restrict__ sdeg, const float* __restrict__ bias,
        const float* __restrict__ scale,
        __hip_bfloat16* out16, int ntiles) {
    const int lane = threadIdx.x & 63;
    const int col = lane & 15, quad = lane >> 4;
    int wv = (blockIdx.x * blockDim.x + threadIdx.x) >> 6;
    int nwv = (gridDim.x * blockDim.x) >> 6;
    const uint4* wfq = (const uint4*)wf;
    for (int tile = wv; tile < ntiles; tile += nwv) {
        int base = tile * 16;
        float4v acc0 = {0.f, 0.f, 0.f, 0.f};
        float4v acc1 = {0.f, 0.f, 0.f, 0.f};
        float4v acc2 = {0.f, 0.f, 0.f, 0.f};
        float4v acc3 = {0.f, 0.f, 0.f, 0.f};
        for (int g = 0; g < ngemm; ++g) {
            const uint4* ga = (const uint4*)(gbase + (size_t)g * gstride);
            const uint4* wg = wfq + (size_t)g * 512;
#pragma unroll
            for (int t = 0; t < 2; ++t) {
                short8 a = as_s8(ga[(size_t)(base + col) * 8 + t * 4 + quad]);
                short8 b0 = as_s8(wg[(t * 4 + 0) * 64 + lane]);
                short8 b1 = as_s8(wg[(t * 4 + 1) * 64 + lane]);
                short8 b2 = as_s8(wg[(t * 4 + 2) * 64 + lane]);
                short8 b3 = as_s8(wg[(t * 4 + 3) * 64 + lane]);
                acc0 = __builtin_amdgcn_mfma_f32_16x16x32_bf16(a, b0, acc0, 0, 0, 0);
                acc1 = __builtin_amdgcn_mfma_f32_16x16x32_bf16(a, b1, acc1, 0, 0, 0);
                acc2 = __builtin_amdgcn_mfma_f32_16x16x32_bf16(a, b2, acc2, 0, 0, 0);
                acc3 = __builtin_amdgcn_mfma_f32_16x16x32_bf16(a, b3, acc3, 0, 0, 0);
            }
        }
#pragma unroll
        for (int r = 0; r < 4; ++r) {
            int nd = base + quad * 4 + r;
            float sd = sdeg[nd];
            float sc = scale ? scale[nd] : 1.0f;
            float f0 = sc * tanhf(sd * acc0[r] + bias[0 * 16 + col]);
            float f1 = sc * tanhf(sd * acc1[r] + bias[1 * 16 + col]);
            float f2 = sc * tanhf(sd * acc2[r] + bias[2 * 16 + col]);
            float f3 = sc * tanhf(sd * acc3[r] + bias[3 * 16 + col]);
            out16[(size_t)nd * 64 + 0 * 16 + col] = __float2bfloat16(f0);
            out16[(size_t)nd * 64 + 1 * 16 + col] = __float2bfloat16(f1);
            out16[(size_t)nd * 64 + 2 * 16 + col] = __float2bfloat16(f2);
            out16[(size_t)nd * 64 + 3 * 16 + col] = __float2bfloat16(f3);
        }
    }
}

// ---------------- MFMA head: out = v16 @ Wc + bc ----------------

__global__ __launch_bounds__(256) void head_kernel(
        const __hip_bfloat16* __restrict__ v16, const __hip_bfloat16* __restrict__ wfc,
        const float* __restrict__ bc, float* __restrict__ out, int ntiles) {
    const int lane = threadIdx.x & 63;
    const int col = lane & 15, quad = lane >> 4;
    int wv = (blockIdx.x * blockDim.x + threadIdx.x) >> 6;
    int nwv = (gridDim.x * blockDim.x) >> 6;
    const uint4* va = (const uint4*)v16;
    const uint4* wg = (const uint4*)wfc;
    for (int tile = wv; tile < ntiles; tile += nwv) {
        int base = tile * 16;
        float4v acc0 = {0.f, 0.f, 0.f, 0.f};
        float4v acc1 = {0.f, 0.f, 0.f, 0.f};
        float4v acc2 = {0.f, 0.f, 0.f, 0.f};
        float4v acc3 = {0.f, 0.f, 0.f, 0.f};
#pragma unroll
        for (int t = 0; t < 2; ++t) {
            short8 a = as_s8(va[(size_t)(base + col) * 8 + t * 4 + quad]);
            short8 b0 = as_s8(wg[(t * 4 + 0) * 64 + lane]);
            short8 b1 = as_s8(wg[(t * 4 + 1) * 64 + lane]);
            short8 b2 = as_s8(wg[(t * 4 + 2) * 64 + lane]);
            short8 b3 = as_s8(wg[(t * 4 + 3) * 64 + lane]);
            acc0 = __builtin_amdgcn_mfma_f32_16x16x32_bf16(a, b0, acc0, 0, 0, 0);
            acc1 = __builtin_amdgcn_mfma_f32_16x16x32_bf16(a, b1, acc1, 0, 0, 0);
            acc2 = __builtin_amdgcn_mfma_f32_16x16x32_bf16(a, b2, acc2, 0, 0, 0);
            acc3 = __builtin_amdgcn_mfma_f32_16x16x32_bf16(a, b3, acc3, 0, 0, 0);
        }
#pragma unroll
        for (int r = 0; r < 4; ++r) {
            int nd = base + quad * 4 + r;
            out[(size_t)nd * 64 + 0 * 16 + col] = acc0[r] + bc[0 * 16 + col];
            out[(size_t)nd * 64 + 1 * 16 + col] = acc1[r] + bc[1 * 16 + col];
            out[(size_t)nd * 64 + 2 * 16 + col] = acc2[r] + bc[2 * 16 + col];
            out[(size_t)nd * 64 + 3 * 16 + col] = acc3[r] + bc[3 * 16 + col];
        }
    }
}

// ---------------- launch ----------------

extern "C" void kernel_launch(void* const* d_in, const int* in_sizes, int n_in,
                              void* d_out, int out_size, void* d_ws, size_t ws_size,
                              hipStream_t stream) {
    const float* x  = (const float*)d_in[0];
    const int*   ei = (const int*)d_in[1];   // [2, E] int32
    const float* w1 = (const float*)d_in[2]; // [11,64,64]
    const float* b1 = (const float*)d_in[3];
    const float* w2 = (const float*)d_in[4]; // [4,64,64]
    const float* b2 = (const float*)d_in[5];
    const float* wc = (const float*)d_in[6];
    const float* bc = (const float*)d_in[7];
    float* out = (float*)d_out;

    const int N = in_sizes[0] / 64;
    const int E = in_sizes[1] / 2;
    const int K1 = 10, K2 = 3;
    const int* row = ei;
    const int* col = ei + E;
    const int Epad = E + (PAD - 1) * N + 64;
    const int NBUF = 11;
    const int nbkt = (N + 511) >> 9;
    const size_t gstride = (((size_t)(N + 1) * 64) + 127) & ~(size_t)127;

    // workspace carve (256B aligned)
    char* base = (char*)d_ws;
    auto alloc = [&](size_t bytes) { void* p = (void*)base; base += (bytes + 255) & ~(size_t)255; return p; };
    int*   deg      = (int*)alloc((size_t)N * 4);
    int*   rowptr   = (int*)alloc((size_t)(N + 1) * 4);
    int*   chunkSum = (int*)alloc(256 * 4);
    int*   chunkOff = (int*)alloc(256 * 4);
    int*   blockHist= (int*)alloc((size_t)NBKT_MAX * 256 * 4);
    int*   bktTot   = (int*)alloc((size_t)NBKT_MAX * 4);
    int*   bktOff   = (int*)alloc((size_t)NBKT_MAX * 4);
    float* dinv     = (float*)alloc((size_t)N * 4);
    float* dinv2    = (float*)alloc((size_t)N * 4);
    float* sdeg     = (float*)alloc((size_t)N * 4);
    int*   srcs     = (int*)alloc((size_t)Epad * 4);
    __hip_bfloat16* wf    = (__hip_bfloat16*)alloc((size_t)16 * 4096 * 2);
    __hip_bfloat16* gbase = (__hip_bfloat16*)alloc((size_t)NBUF * gstride * 2);

    auto G = [&](int k) { return gbase + (size_t)k * gstride; };
    int2* pairs = (int2*)G(9);            // dead until hop 9; consumed before hops
    __hip_bfloat16* vbuf16 = G(5);        // free during layer-2 (hops use G(1..4))

    const int numChunks = (N + 511) / 512;
    const int nBlocks = (N + 255) / 256;
    const int xBlocks = (N * 64 + 255) / 256;
    const int gBlocks = 2048;
    const int ntiles = (N + 15) / 16;

    // ---- bucketed CSR build + degree ----
    hist_kernel<<<256, 256, 0, stream>>>(col, blockHist, E, nbkt);
    bscan_kernel<<<nbkt, 256, 0, stream>>>(blockHist, bktTot, nbkt);
    scan_small<<<1, 256, 0, stream>>>(bktTot, bktOff, nbkt);
    scatter_kernel<<<256, 256, 0, stream>>>(row, col, blockHist, bktOff, pairs, E, nbkt);
    deg_pairs_kernel<<<nbkt, 256, 0, stream>>>(pairs, bktOff, bktTot, deg, dinv, dinv2, sdeg, N);
    scan_phaseA<<<numChunks, 512, 0, stream>>>(deg, chunkSum, N);
    scan_small<<<1, 256, 0, stream>>>(chunkSum, chunkOff, numChunks);
    scan_phaseC<<<numChunks, 512, 0, stream>>>(deg, chunkOff, rowptr, N);
    cluster_kernel<<<nbkt, 256, 0, stream>>>(pairs, bktOff, bktTot, rowptr, srcs, N);

    wcvt_kernel<<<(16 * 4096 + 255) / 256, 256, 0, stream>>>(w1, w2, wc, wf);
    zero_pads_kernel<<<(NBUF * 64 + 255) / 256, 256, 0, stream>>>(gbase, gstride, NBUF, N);
    cvt_g_kernel<<<xBlocks, 256, 0, stream>>>(x, dinv, G(0), N);

    // ---- layer 1: 10 pure-gather hops: G(k-1) -> G(k) ----
    for (int k = 1; k <= K1; ++k)
        hop_kernel<<<gBlocks, 256, 0, stream>>>(G(k - 1), srcs, rowptr, dinv2, G(k), N);

    // ---- layer-1 GEMMs + tanh + next-layer g -> G(1) (tile-local overwrite: safe) ----
    final_kernel<<<gBlocks, 256, 0, stream>>>(gbase, gstride, 11, wf, sdeg, b1, dinv,
                                              G(1), ntiles);

    // ---- layer 2: 3 hops: G(1)->G(2)->G(3)->G(4) ----
    for (int k = 1; k <= K2; ++k)
        hop_kernel<<<gBlocks, 256, 0, stream>>>(G(k), srcs, rowptr, dinv2, G(k + 1), N);

    // ---- layer-2 GEMMs + tanh -> v16 (bf16) ----
    final_kernel<<<gBlocks, 256, 0, stream>>>(G(1), gstride, 4, wf + (size_t)11 * 4096,
                                              sdeg, b2, nullptr, vbuf16, ntiles);

    // ---- MFMA head: out = v16 @ wc + bc ----
    head_kernel<<<gBlocks, 256, 0, stream>>>(vbuf16, wf + (size_t)15 * 4096, bc, out, ntiles);
}